// Round 2
// baseline (1182.460 us; speedup 1.0000x reference)
//
#include <hip/hip_runtime.h>
#include <math.h>

#define B_  2
#define C_  128
#define N_  6000
#define M_  1500
#define H_  4
#define DH_ 32

// ---------------------------------------------------------------- conv1 (GEMM)
// Y[b,o,p] = act(sum_c W[o,c] * X[b,c,p] + bias[o]) (+resid) ; X from Xa (ch<csplit) else Xb.
// 64x64 tile, 4x4 per thread, LDS-staged. Epilogues:
//   bs/bsh non-null -> y = relu(y*bs+bsh)   (BN eval fold)
//   resid non-null  -> fin = y + resid      (resid has Cout channels)
//   Yf: fp32 out (yfraw? pre-resid : final); Yh: second fp32 out (final)
template<int CIN>
__global__ __launch_bounds__(256) void conv_kernel(
    const float* __restrict__ Xa, const float* __restrict__ Xb,
    const float* __restrict__ W, const float* __restrict__ bias,
    const float* __restrict__ bs, const float* __restrict__ bsh,
    const float* __restrict__ resid,
    float* __restrict__ Yf, float* __restrict__ Yh,
    int P, int Cout, int csplit, int strideXa, int strideXb, int yfraw)
{
    constexpr int CK = 16;
    __shared__ alignas(16) float Xs[CK][64];
    __shared__ alignas(16) float Ws[CK][68];   // row = 272B = 17*16B: float4-aligned, pad breaks stride
    const int tid = threadIdx.x;
    const int tx = tid & 15, ty = tid >> 4;
    const int b  = blockIdx.z;
    const int o0 = blockIdx.y * 64;
    const int p0 = blockIdx.x * 64;
    float acc[4][4] = {};
    const long offA = (long)b * strideXa;
    const long offB = (long)b * strideXb;

    for (int cc = 0; cc < CIN; cc += CK) {
        #pragma unroll
        for (int i = 0; i < 4; ++i) {              // stage X: 16x64
            int e = tid + 256 * i;
            int c = e >> 6, j = e & 63;
            int ch = cc + c;
            int pp = p0 + j; if (pp >= P) pp = P - 1;
            float v = (ch < csplit) ? Xa[offA + (long)ch * P + pp]
                                    : Xb[offB + (long)(ch - csplit) * P + pp];
            Xs[c][j] = v;
        }
        #pragma unroll
        for (int i = 0; i < 4; ++i) {              // stage W^T: 16x64
            int e = tid + 256 * i;
            int o = e >> 4, c = e & 15;
            Ws[c][o] = W[(long)(o0 + o) * CIN + cc + c];
        }
        __syncthreads();
        #pragma unroll
        for (int kk = 0; kk < CK; ++kk) {
            const float4 wv = *(const float4*)&Ws[kk][ty * 4];
            const float4 xv = *(const float4*)&Xs[kk][tx * 4];
            const float w[4] = {wv.x, wv.y, wv.z, wv.w};
            const float x[4] = {xv.x, xv.y, xv.z, xv.w};
            #pragma unroll
            for (int i = 0; i < 4; ++i)
                #pragma unroll
                for (int j = 0; j < 4; ++j)
                    acc[i][j] += w[i] * x[j];
        }
        __syncthreads();
    }

    const long strideY = (long)Cout * P;
    #pragma unroll
    for (int i = 0; i < 4; ++i) {
        const int o = o0 + ty * 4 + i;
        const float bi = bias[o];
        float sv = 0.f, shv = 0.f;
        if (bs) { sv = bs[o]; shv = bsh[o]; }
        #pragma unroll
        for (int j = 0; j < 4; ++j) {
            const int p = p0 + tx * 4 + j;
            if (p < P) {
                float v = acc[i][j] + bi;
                if (bs) v = fmaxf(v * sv + shv, 0.f);
                float fin = v;
                const long idx = (long)b * strideY + (long)o * P + p;
                if (resid) fin += resid[idx];
                if (Yf) Yf[idx] = yfraw ? v : fin;
                if (Yh) Yh[idx] = fin;
            }
        }
    }
}

// ---------------------------------------------------------------- flash attention (partials)
// Per block: 512 queries (2/thread), one key-split. Online softmax, unnormalized partials.
__global__ __launch_bounds__(256) void attn_partial(
    const float* __restrict__ Q, const float* __restrict__ K, const float* __restrict__ V,
    const float* __restrict__ lgin,     // null -> no kv mask
    float* __restrict__ pm, float* __restrict__ pl, float* __restrict__ pacc,
    int Nq, int Nk, int KS, int chunkLen)
{
    __shared__ alignas(16) float ks[64][36];   // [key][dh], rows 144B (9*16B aligned)
    __shared__ alignas(16) float vs[64][36];
    __shared__ float msk[64];
    const int tid = threadIdx.x;
    const int bh = blockIdx.y, b = bh >> 2, h = bh & 3;
    const int split = blockIdx.z;
    const int p0 = blockIdx.x * 512 + tid;
    const int p1 = p0 + 256;
    const int pc0 = p0 < Nq ? p0 : Nq - 1;
    const int pc1 = p1 < Nq ? p1 : Nq - 1;
    const long qoff = ((long)b * C_ + h * DH_) * Nq;
    const long koff = ((long)b * C_ + h * DH_) * Nk;
    const float invs = 0.17677669529663687f;   // 1/sqrt(32)
    const float MASKV = -176776.695f;          // -1e6/sqrt(32)

    float qv0[32], qv1[32], av0[32], av1[32];
    #pragma unroll
    for (int d = 0; d < 32; ++d) {
        qv0[d] = Q[qoff + (long)d * Nq + pc0] * invs;
        qv1[d] = Q[qoff + (long)d * Nq + pc1] * invs;
        av0[d] = 0.f; av1[d] = 0.f;
    }
    float mi0 = -INFINITY, li0 = 0.f, mi1 = -INFINITY, li1 = 0.f;

    const int kbeg = split * chunkLen;
    const int kend = min(Nk, kbeg + chunkLen);
    for (int m0 = kbeg; m0 < kend; m0 += 64) {
        #pragma unroll
        for (int i = 0; i < 8; ++i) {          // stage 64 keys x 32 dh of K and V
            int e = tid + 256 * i;
            int d = e & 31, j = e >> 5;
            int mm = m0 + j; int mmc = mm < Nk ? mm : Nk - 1;
            ks[j][d] = K[koff + (long)d * Nk + mmc];
            vs[j][d] = V[koff + (long)d * Nk + mmc];
        }
        if (tid < 64) {
            int mm = m0 + tid;
            bool ok = (mm < kend);
            if (ok && lgin) ok = (lgin[(long)b * Nk + mm] > 0.f);
            msk[tid] = ok ? 1.f : -1.f;
        }
        __syncthreads();

        for (int j0 = 0; j0 < 64; j0 += 8) {
            float s0[8], s1[8];
            #pragma unroll
            for (int jj = 0; jj < 8; ++jj) {
                const int j = j0 + jj;
                const float4* kp = (const float4*)&ks[j][0];
                float a00 = 0.f, a01 = 0.f, a10 = 0.f, a11 = 0.f;
                #pragma unroll
                for (int d4 = 0; d4 < 8; ++d4) {
                    float4 kv = kp[d4];
                    a00 += qv0[4*d4+0]*kv.x; a01 += qv0[4*d4+1]*kv.y;
                    a00 += qv0[4*d4+2]*kv.z; a01 += qv0[4*d4+3]*kv.w;
                    a10 += qv1[4*d4+0]*kv.x; a11 += qv1[4*d4+1]*kv.y;
                    a10 += qv1[4*d4+2]*kv.z; a11 += qv1[4*d4+3]*kv.w;
                }
                const bool on = msk[j] > 0.f;
                s0[jj] = on ? (a00 + a01) : MASKV;
                s1[jj] = on ? (a10 + a11) : MASKV;
            }
            float c0 = s0[0], c1 = s1[0];
            #pragma unroll
            for (int jj = 1; jj < 8; ++jj) { c0 = fmaxf(c0, s0[jj]); c1 = fmaxf(c1, s1[jj]); }
            const float mn0 = fmaxf(mi0, c0), mn1 = fmaxf(mi1, c1);
            const float cor0 = __expf(mi0 - mn0), cor1 = __expf(mi1 - mn1);
            li0 *= cor0; li1 *= cor1;
            #pragma unroll
            for (int d = 0; d < 32; ++d) { av0[d] *= cor0; av1[d] *= cor1; }
            #pragma unroll
            for (int jj = 0; jj < 8; ++jj) {
                const int j = j0 + jj;
                const float e0 = __expf(s0[jj] - mn0), e1 = __expf(s1[jj] - mn1);
                li0 += e0; li1 += e1;
                const float4* vp = (const float4*)&vs[j][0];
                #pragma unroll
                for (int d4 = 0; d4 < 8; ++d4) {
                    float4 vv = vp[d4];
                    av0[4*d4+0] += e0*vv.x; av0[4*d4+1] += e0*vv.y;
                    av0[4*d4+2] += e0*vv.z; av0[4*d4+3] += e0*vv.w;
                    av1[4*d4+0] += e1*vv.x; av1[4*d4+1] += e1*vv.y;
                    av1[4*d4+2] += e1*vv.z; av1[4*d4+3] += e1*vv.w;
                }
            }
            mi0 = mn0; mi1 = mn1;
        }
        __syncthreads();
    }

    const long base = (long)bh * KS + split;
    if (p0 < Nq) {
        pm[base * Nq + p0] = mi0; pl[base * Nq + p0] = li0;
        #pragma unroll
        for (int d = 0; d < 32; ++d) pacc[(base * 32 + d) * Nq + p0] = av0[d];
    }
    if (p1 < Nq) {
        pm[base * Nq + p1] = mi1; pl[base * Nq + p1] = li1;
        #pragma unroll
        for (int d = 0; d < 32; ++d) pacc[(base * 32 + d) * Nq + p1] = av1[d];
    }
}

// ---------------------------------------------------------------- combine splits
__global__ __launch_bounds__(256) void attn_combine(
    const float* __restrict__ pm, const float* __restrict__ pl, const float* __restrict__ pacc,
    float* __restrict__ OUT, int Nq, int KS)
{
    const int tid = threadIdx.x;
    const int bh = blockIdx.y, b = bh >> 2, h = bh & 3;
    const int p = blockIdx.x * 256 + tid;
    if (p >= Nq) return;
    float mg = -INFINITY;
    for (int s = 0; s < KS; ++s) mg = fmaxf(mg, pm[((long)bh * KS + s) * Nq + p]);
    float acc[32];
    #pragma unroll
    for (int d = 0; d < 32; ++d) acc[d] = 0.f;
    float lg = 0.f;
    for (int s = 0; s < KS; ++s) {
        const long base = (long)bh * KS + s;
        const float w = __expf(pm[base * Nq + p] - mg);
        lg += pl[base * Nq + p] * w;
        #pragma unroll
        for (int d = 0; d < 32; ++d) acc[d] += pacc[(base * 32 + d) * Nq + p] * w;
    }
    const float inv = 1.f / lg;
    #pragma unroll
    for (int d = 0; d < 32; ++d)
        OUT[((long)b * C_ + h * DH_ + d) * Nq + p] = acc[d] * inv;
}

// ---------------------------------------------------------------- fused conv + InstanceNorm + affine + ReLU
template<int CIN>
__global__ __launch_bounds__(256) void inorm_kernel(
    const float* __restrict__ X, const float* __restrict__ W, const float* __restrict__ bias,
    const float* __restrict__ sc, const float* __restrict__ sh,
    float* __restrict__ Y, int Npos)
{
    __shared__ float wrow[CIN];
    __shared__ float ybuf[N_];
    __shared__ float rsum[4], rsq[4], stats[2];
    const int tid = threadIdx.x;
    const int o = blockIdx.x, b = blockIdx.y, Cout = gridDim.x;
    for (int c = tid; c < CIN; c += 256) wrow[c] = W[o * CIN + c];
    __syncthreads();
    const float bi = bias[o];
    float ls = 0.f, lq = 0.f;
    for (int p = tid; p < Npos; p += 256) {
        float a = bi;
        #pragma unroll 8
        for (int c = 0; c < CIN; ++c) a += wrow[c] * X[((long)b * CIN + c) * Npos + p];
        ybuf[p] = a; ls += a; lq += a * a;
    }
    #pragma unroll
    for (int m = 32; m; m >>= 1) { ls += __shfl_xor(ls, m); lq += __shfl_xor(lq, m); }
    const int lane = tid & 63, wid = tid >> 6;
    if (lane == 0) { rsum[wid] = ls; rsq[wid] = lq; }
    __syncthreads();
    if (tid == 0) {
        const float S  = rsum[0] + rsum[1] + rsum[2] + rsum[3];
        const float Q2 = rsq[0] + rsq[1] + rsq[2] + rsq[3];
        const float mu = S / Npos;
        const float var = Q2 / Npos - mu * mu;   // biased, matches InstanceNorm1d
        stats[0] = mu; stats[1] = rsqrtf(var + 1e-3f);
    }
    __syncthreads();
    const float k1 = stats[1] * sc[o];
    const float k2 = sh[o] - stats[0] * k1;
    for (int p = tid; p < Npos; p += 256)
        Y[((long)b * Cout + o) * Npos + p] = fmaxf(ybuf[p] * k1 + k2, 0.f);
}

// ---------------------------------------------------------------- final 4->1 conv -> logits
__global__ __launch_bounds__(256) void logits_kernel(
    const float* __restrict__ X, const float* __restrict__ W4, const float* __restrict__ b4,
    float* __restrict__ out, int Npos)
{
    const int idx = blockIdx.x * 256 + threadIdx.x;
    if (idx >= B_ * Npos) return;
    const int b = idx / Npos, n = idx % Npos;
    float acc = b4[0];
    #pragma unroll
    for (int c = 0; c < 4; ++c)
        acc += W4[c] * X[((long)b * 4 + c) * Npos + n];
    out[idx] = acc;
}

// ================================================================ host
extern "C" void kernel_launch(void* const* d_in, const int* in_sizes, int n_in,
                              void* d_out, int out_size, void* d_ws, size_t ws_size,
                              hipStream_t stream)
{
    const float* dX   = (const float*)d_in[1];    // d        [2,128,6000]
    const float* fpX  = (const float*)d_in[2];    // feat_piece [2,128,1500]
    const float* lgin = (const float*)d_in[3];    // logits_in [2,6000]
    const float* Wq = (const float*)d_in[4];  const float* bq = (const float*)d_in[5];
    const float* Wk = (const float*)d_in[6];  const float* bk = (const float*)d_in[7];
    const float* Wv = (const float*)d_in[8];  const float* bv = (const float*)d_in[9];
    const float* Wm = (const float*)d_in[10]; const float* bm = (const float*)d_in[11];
    const float* Wc1= (const float*)d_in[12]; const float* bc1= (const float*)d_in[13];
    const float* bns= (const float*)d_in[14]; const float* bnsh=(const float*)d_in[15];
    const float* Wc2= (const float*)d_in[16]; const float* bc2= (const float*)d_in[17];
    const float* iW1= (const float*)d_in[18]; const float* ib1= (const float*)d_in[19];
    const float* s1 = (const float*)d_in[20]; const float* h1 = (const float*)d_in[21];
    const float* iW2= (const float*)d_in[22]; const float* ib2= (const float*)d_in[23];
    const float* s2 = (const float*)d_in[24]; const float* h2 = (const float*)d_in[25];
    const float* iW3= (const float*)d_in[26]; const float* ib3= (const float*)d_in[27];
    const float* s3 = (const float*)d_in[28]; const float* h3 = (const float*)d_in[29];
    const float* iW4= (const float*)d_in[30]; const float* ib4= (const float*)d_in[31];

    float* out_d      = (float*)d_out;                 // [2,128,6000]
    float* out_logits = out_d + (long)B_ * C_ * N_;    // [2,6000]

    float* f = (float*)d_ws;
    long off = 0;
    auto alloc = [&](long n) { float* p = f + off; off += n; return p; };
    float* featA = alloc((long)B_ * C_ * M_);      // 384k
    float* featB = alloc((long)B_ * C_ * M_);      // 384k
    float* qb    = alloc((long)B_ * C_ * N_);      // q / addm (reused)
    float* kb    = alloc((long)B_ * C_ * N_);
    float* vb    = alloc((long)B_ * C_ * N_);
    float* addb  = alloc((long)B_ * C_ * N_);
    float* xb    = alloc((long)B_ * C_ * N_);      // d_new - d_old (raw Wc2 out)
    float* x1b   = alloc((long)B_ * 64 * N_);
    float* x2b   = alloc((long)B_ * 16 * N_);
    float* x3b   = alloc((long)B_ * 4 * N_);
    float* pmb   = alloc(200000);                  // >= B*H*KS*Nq max (192k)
    float* plb   = alloc(200000);
    float* big   = alloc(6200000);                 // pacc (<=6.144M) UNION hb (<=3.072M); disjoint lifetimes
    float* pab = big;
    float* hb  = big;
    (void)ws_size; (void)in_sizes; (void)n_in; (void)out_size;
    // total ~16.1M floats = ~64.5 MB

    auto conv = [&](int CIN, const float* Xa, const float* Xb, int csplit,
                    const float* W, const float* bias, const float* bsp, const float* bshp,
                    const float* resid, float* Yf, float* Yh,
                    int P, int Cout, int strideXa, int strideXb, int yfraw) {
        dim3 g((P + 63) / 64, Cout / 64, B_);
        if (CIN == 128)
            conv_kernel<128><<<g, 256, 0, stream>>>(Xa, Xb, W, bias, bsp, bshp, resid,
                                                    Yf, Yh, P, Cout, csplit, strideXa, strideXb, yfraw);
        else
            conv_kernel<256><<<g, 256, 0, stream>>>(Xa, Xb, W, bias, bsp, bshp, resid,
                                                    Yf, Yh, P, Cout, csplit, strideXa, strideXb, yfraw);
    };

    auto attn_layer = [&](const float* x1, const float* x2, int Nq, int Nk,
                          const float* maskl, int li, int KS,
                          float* outF, float* outH, int yfraw) {
        const float* Wqi = Wq + (long)li * C_ * C_;     const float* bqi = bq + li * C_;
        const float* Wki = Wk + (long)li * C_ * C_;     const float* bki = bk + li * C_;
        const float* Wvi = Wv + (long)li * C_ * C_;     const float* bvi = bv + li * C_;
        const float* Wmi = Wm + (long)li * C_ * C_;     const float* bmi = bm + li * C_;
        const float* Wc1i= Wc1 + (long)li * 2*C_*2*C_;  const float* bc1i= bc1 + li * 2*C_;
        const float* bnsi= bns + li * 2*C_;             const float* bnshi= bnsh + li * 2*C_;
        const float* Wc2i= Wc2 + (long)li * C_ * 2*C_;  const float* bc2i= bc2 + li * C_;

        conv(128, x1, nullptr, 128, Wqi, bqi, nullptr, nullptr, nullptr, qb, nullptr, Nq, 128, C_*Nq, 0, 0);
        conv(128, x2, nullptr, 128, Wki, bki, nullptr, nullptr, nullptr, kb, nullptr, Nk, 128, C_*Nk, 0, 0);
        conv(128, x2, nullptr, 128, Wvi, bvi, nullptr, nullptr, nullptr, vb, nullptr, Nk, 128, C_*Nk, 0, 0);
        const int chunkLen = (Nk + KS - 1) / KS;
        attn_partial<<<dim3((Nq + 511) / 512, B_ * H_, KS), 256, 0, stream>>>(
            qb, kb, vb, maskl, pmb, plb, pab, Nq, Nk, KS, chunkLen);
        attn_combine<<<dim3((Nq + 255) / 256, B_ * H_), 256, 0, stream>>>(
            pmb, plb, pab, addb, Nq, KS);
        conv(128, addb, nullptr, 128, Wmi, bmi, nullptr, nullptr, nullptr, qb, nullptr, Nq, 128, C_*Nq, 0, 0);
        conv(256, x1, qb, 128, Wc1i, bc1i, bnsi, bnshi, nullptr, hb, nullptr, Nq, 256, C_*Nq, C_*Nq, 0);
        conv(256, hb, nullptr, 256, Wc2i, bc2i, nullptr, nullptr, x1, outF, outH, Nq, 128, 2*C_*Nq, 0, yfraw);
    };

    // layer 0: feat = attn(feat_piece <- d, masked kv)   KS=16 -> 3*8*16=384 blocks
    attn_layer(fpX, dX, M_, N_, lgin, 0, 16, featA, nullptr, 0);
    // layer 1: feat = attn(feat <- feat)                 KS=16
    attn_layer(featA, featA, M_, M_, nullptr, 1, 16, featB, nullptr, 0);
    // layer 2: d_new = attn(d <- feat); final -> out_d, raw conv (= d_new-d_old) -> xb.  KS=4 -> 12*8*4=384
    attn_layer(dX, featB, N_, M_, nullptr, 2, 4, xb, out_d, 1);

    // instance-norm conv stack
    inorm_kernel<128><<<dim3(64, B_), 256, 0, stream>>>(xb,  iW1, ib1, s1, h1, x1b, N_);
    inorm_kernel<64> <<<dim3(16, B_), 256, 0, stream>>>(x1b, iW2, ib2, s2, h2, x2b, N_);
    inorm_kernel<16> <<<dim3(4,  B_), 256, 0, stream>>>(x2b, iW3, ib3, s3, h3, x3b, N_);
    logits_kernel<<<dim3((B_ * N_ + 255) / 256), 256, 0, stream>>>(x3b, iW4, ib4, out_logits, N_);
}

// Round 3
// 928.536 us; speedup vs baseline: 1.2735x; 1.2735x over previous
//
#include <hip/hip_runtime.h>
#include <math.h>

#define B_  2
#define C_  128
#define N_  6000
#define M_  1500
#define H_  4
#define DH_ 32

// ---------------------------------------------------------------- conv1 (GEMM)
// Y[b,o,p] = act(sum_c W[o,c] * X[b,c,p] + bias[o]) (+resid) ; X from Xa (ch<csplit) else Xb.
// 64x64 tile, 4x4 per thread, LDS-staged.
template<int CIN>
__global__ __launch_bounds__(256) void conv_kernel(
    const float* __restrict__ Xa, const float* __restrict__ Xb,
    const float* __restrict__ W, const float* __restrict__ bias,
    const float* __restrict__ bs, const float* __restrict__ bsh,
    const float* __restrict__ resid,
    float* __restrict__ Yf, float* __restrict__ Yh,
    int P, int Cout, int csplit, int strideXa, int strideXb, int yfraw)
{
    constexpr int CK = 16;
    __shared__ alignas(16) float Xs[CK][64];
    __shared__ alignas(16) float Ws[CK][68];
    const int tid = threadIdx.x;
    const int tx = tid & 15, ty = tid >> 4;
    const int b  = blockIdx.z;
    const int o0 = blockIdx.y * 64;
    const int p0 = blockIdx.x * 64;
    float acc[4][4] = {};
    const long offA = (long)b * strideXa;
    const long offB = (long)b * strideXb;

    for (int cc = 0; cc < CIN; cc += CK) {
        #pragma unroll
        for (int i = 0; i < 4; ++i) {              // stage X: 16x64
            int e = tid + 256 * i;
            int c = e >> 6, j = e & 63;
            int ch = cc + c;
            int pp = p0 + j; if (pp >= P) pp = P - 1;
            float v = (ch < csplit) ? Xa[offA + (long)ch * P + pp]
                                    : Xb[offB + (long)(ch - csplit) * P + pp];
            Xs[c][j] = v;
        }
        #pragma unroll
        for (int i = 0; i < 4; ++i) {              // stage W^T: 16x64
            int e = tid + 256 * i;
            int o = e >> 4, c = e & 15;
            Ws[c][o] = W[(long)(o0 + o) * CIN + cc + c];
        }
        __syncthreads();
        #pragma unroll
        for (int kk = 0; kk < CK; ++kk) {
            const float4 wv = *(const float4*)&Ws[kk][ty * 4];
            const float4 xv = *(const float4*)&Xs[kk][tx * 4];
            const float w[4] = {wv.x, wv.y, wv.z, wv.w};
            const float x[4] = {xv.x, xv.y, xv.z, xv.w};
            #pragma unroll
            for (int i = 0; i < 4; ++i)
                #pragma unroll
                for (int j = 0; j < 4; ++j)
                    acc[i][j] += w[i] * x[j];
        }
        __syncthreads();
    }

    const long strideY = (long)Cout * P;
    #pragma unroll
    for (int i = 0; i < 4; ++i) {
        const int o = o0 + ty * 4 + i;
        const float bi = bias[o];
        float sv = 0.f, shv = 0.f;
        if (bs) { sv = bs[o]; shv = bsh[o]; }
        #pragma unroll
        for (int j = 0; j < 4; ++j) {
            const int p = p0 + tx * 4 + j;
            if (p < P) {
                float v = acc[i][j] + bi;
                if (bs) v = fmaxf(v * sv + shv, 0.f);
                float fin = v;
                const long idx = (long)b * strideY + (long)o * P + p;
                if (resid) fin += resid[idx];
                if (Yf) Yf[idx] = yfraw ? v : fin;
                if (Yh) Yh[idx] = fin;
            }
        }
    }
}

// ---------------------------------------------------------------- flash attention (partials)
// 256 queries/block, 1 query/thread, one key-split/z. Register-double-buffered K/V staging.
// Mask folded into additive per-key bias (0 valid / MASKV masked / -inf out-of-range).
__global__ __launch_bounds__(256) void attn_partial(
    const float* __restrict__ Q, const float* __restrict__ K, const float* __restrict__ V,
    const float* __restrict__ lgin,     // null -> no kv mask
    float* __restrict__ pm, float* __restrict__ pl, float* __restrict__ pacc,
    int Nq, int Nk, int KS, int chunkLen)   // chunkLen multiple of 64
{
    __shared__ alignas(16) float ks[64][36];   // [key][dh] rows 144B
    __shared__ alignas(16) float vs[64][36];
    __shared__ float biasS[64];
    const int tid = threadIdx.x;
    const int bh = blockIdx.y, b = bh >> 2, h = bh & 3;
    const int split = blockIdx.z;
    const int p0 = blockIdx.x * 256 + tid;
    const int pc0 = p0 < Nq ? p0 : Nq - 1;
    const long qoff = ((long)b * C_ + h * DH_) * Nq;
    const long koff = ((long)b * C_ + h * DH_) * Nk;
    const float invs = 0.17677669529663687f;   // 1/sqrt(32)
    const float MASKV = -176776.695f;          // -1e6/sqrt(32)

    float qv[32], av[32];
    #pragma unroll
    for (int d = 0; d < 32; ++d) {
        qv[d] = Q[qoff + (long)d * Nq + pc0] * invs;
        av[d] = 0.f;
    }
    float mi = -INFINITY, li = 0.f;

    const int kbeg = split * chunkLen;
    const int kend = min(Nk, kbeg + chunkLen);

    if (kbeg < kend) {
        float rk[8], rv[8];
        const int sd = tid & 31, sj = tid >> 5;     // staged (dim, key-base) for this thread
        auto stage = [&](int m0) {
            #pragma unroll
            for (int i = 0; i < 8; ++i) {
                int mm = m0 + sj + 8 * i; int mmc = mm < Nk ? mm : Nk - 1;
                rk[i] = K[koff + (long)sd * Nk + mmc];
                rv[i] = V[koff + (long)sd * Nk + mmc];
            }
        };
        stage(kbeg);
        for (int m0 = kbeg; m0 < kend; m0 += 64) {
            #pragma unroll
            for (int i = 0; i < 8; ++i) { ks[sj + 8 * i][sd] = rk[i]; vs[sj + 8 * i][sd] = rv[i]; }
            if (tid < 64) {
                int mm = m0 + tid;
                float bv = -INFINITY;                       // out-of-range: zero weight
                if (mm < kend) {
                    bv = 0.f;
                    if (lgin && !(lgin[(long)b * Nk + mm] > 0.f)) bv = MASKV;
                }
                biasS[tid] = bv;
            }
            __syncthreads();
            if (m0 + 64 < kend) stage(m0 + 64);             // prefetch next tile (overlaps compute)

            for (int j0 = 0; j0 < 64; j0 += 8) {
                float s[8];
                #pragma unroll
                for (int jj = 0; jj < 8; ++jj) {
                    const int j = j0 + jj;
                    const float4* kp = (const float4*)&ks[j][0];
                    float a0 = 0.f, a1 = 0.f;
                    #pragma unroll
                    for (int d4 = 0; d4 < 8; ++d4) {
                        float4 kv = kp[d4];
                        a0 += qv[4*d4+0]*kv.x; a1 += qv[4*d4+1]*kv.y;
                        a0 += qv[4*d4+2]*kv.z; a1 += qv[4*d4+3]*kv.w;
                    }
                    s[jj] = a0 + a1 + biasS[j];
                }
                float c = s[0];
                #pragma unroll
                for (int jj = 1; jj < 8; ++jj) c = fmaxf(c, s[jj]);
                const float mn = fmaxf(mi, c);
                const float cor = __expf(mi - mn);
                li *= cor;
                #pragma unroll
                for (int d = 0; d < 32; ++d) av[d] *= cor;
                #pragma unroll
                for (int jj = 0; jj < 8; ++jj) {
                    const int j = j0 + jj;
                    const float e0 = __expf(s[jj] - mn);
                    li += e0;
                    const float4* vp = (const float4*)&vs[j][0];
                    #pragma unroll
                    for (int d4 = 0; d4 < 8; ++d4) {
                        float4 vv = vp[d4];
                        av[4*d4+0] += e0*vv.x; av[4*d4+1] += e0*vv.y;
                        av[4*d4+2] += e0*vv.z; av[4*d4+3] += e0*vv.w;
                    }
                }
                mi = mn;
            }
            __syncthreads();
        }
    }

    const long base = (long)bh * KS + split;
    if (p0 < Nq) {
        pm[base * Nq + p0] = mi; pl[base * Nq + p0] = li;
        #pragma unroll
        for (int d = 0; d < 32; ++d) pacc[(base * 32 + d) * Nq + p0] = av[d];
    }
}

// ---------------------------------------------------------------- combine splits (8 dims/block-z)
__global__ __launch_bounds__(256) void attn_combine(
    const float* __restrict__ pm, const float* __restrict__ pl, const float* __restrict__ pacc,
    float* __restrict__ OUT, int Nq, int KS)
{
    const int tid = threadIdx.x;
    const int bh = blockIdx.y, b = bh >> 2, h = bh & 3;
    const int d0 = blockIdx.z * 8;
    const int p = blockIdx.x * 256 + tid;
    if (p >= Nq) return;
    float mg = -INFINITY;
    for (int s = 0; s < KS; ++s) mg = fmaxf(mg, pm[((long)bh * KS + s) * Nq + p]);
    float acc[8];
    #pragma unroll
    for (int d = 0; d < 8; ++d) acc[d] = 0.f;
    float lg = 0.f;
    for (int s = 0; s < KS; ++s) {
        const long base = (long)bh * KS + s;
        const float w = __expf(pm[base * Nq + p] - mg);
        lg += pl[base * Nq + p] * w;
        #pragma unroll
        for (int d = 0; d < 8; ++d) acc[d] += pacc[(base * 32 + d0 + d) * Nq + p] * w;
    }
    const float inv = 1.f / lg;
    #pragma unroll
    for (int d = 0; d < 8; ++d)
        OUT[((long)b * C_ + h * DH_ + d0 + d) * Nq + p] = acc[d] * inv;
}

// ---------------------------------------------------------------- inorm split stats + normalize
template<int SPLITS>
__global__ __launch_bounds__(256) void inorm_stats(
    const float* __restrict__ Y, float* __restrict__ ps, float* __restrict__ pq,
    int Cout, int Npos)
{
    __shared__ float rsum[4], rsq[4];
    const int tid = threadIdx.x;
    const int o = blockIdx.x, b = blockIdx.y, s = blockIdx.z;
    const int chunk = (Npos + SPLITS - 1) / SPLITS;
    const int pbeg = s * chunk, pend = min(Npos, pbeg + chunk);
    const float* src = Y + ((long)b * Cout + o) * Npos;
    float ls = 0.f, lq = 0.f;
    for (int p = pbeg + tid; p < pend; p += 256) { float a = src[p]; ls += a; lq += a * a; }
    #pragma unroll
    for (int m = 32; m; m >>= 1) { ls += __shfl_xor(ls, m); lq += __shfl_xor(lq, m); }
    const int lane = tid & 63, wid = tid >> 6;
    if (lane == 0) { rsum[wid] = ls; rsq[wid] = lq; }
    __syncthreads();
    if (tid == 0) {
        ps[((long)b * Cout + o) * SPLITS + s] = rsum[0] + rsum[1] + rsum[2] + rsum[3];
        pq[((long)b * Cout + o) * SPLITS + s] = rsq[0] + rsq[1] + rsq[2] + rsq[3];
    }
}

template<int SPLITS>
__global__ __launch_bounds__(256) void inorm_norm(
    const float* __restrict__ Y, const float* __restrict__ ps, const float* __restrict__ pq,
    const float* __restrict__ sc, const float* __restrict__ sh,
    float* __restrict__ OUT, int Cout, int Npos)
{
    const int tid = threadIdx.x;
    const int o = blockIdx.x, b = blockIdx.y, s = blockIdx.z;
    float S = 0.f, Q2 = 0.f;
    #pragma unroll
    for (int i = 0; i < SPLITS; ++i) {
        S  += ps[((long)b * Cout + o) * SPLITS + i];
        Q2 += pq[((long)b * Cout + o) * SPLITS + i];
    }
    const float mu = S / Npos;
    const float var = Q2 / Npos - mu * mu;      // biased, matches InstanceNorm1d
    const float rs = rsqrtf(var + 1e-3f);
    const float k1 = rs * sc[o];
    const float k2 = sh[o] - mu * k1;
    const int chunk = (Npos + SPLITS - 1) / SPLITS;
    const int pbeg = s * chunk, pend = min(Npos, pbeg + chunk);
    const float* src = Y + ((long)b * Cout + o) * Npos;
    float* dst = OUT + ((long)b * Cout + o) * Npos;
    for (int p = pbeg + tid; p < pend; p += 256)
        dst[p] = fmaxf(src[p] * k1 + k2, 0.f);
}

// ---------------------------------------------------------------- fused conv+inorm (small tail convs)
template<int CIN>
__global__ __launch_bounds__(256) void inorm_kernel(
    const float* __restrict__ X, const float* __restrict__ W, const float* __restrict__ bias,
    const float* __restrict__ sc, const float* __restrict__ sh,
    float* __restrict__ Y, int Npos)
{
    __shared__ float wrow[CIN];
    __shared__ float ybuf[N_];
    __shared__ float rsum[4], rsq[4], stats[2];
    const int tid = threadIdx.x;
    const int o = blockIdx.x, b = blockIdx.y, Cout = gridDim.x;
    for (int c = tid; c < CIN; c += 256) wrow[c] = W[o * CIN + c];
    __syncthreads();
    const float bi = bias[o];
    float ls = 0.f, lq = 0.f;
    for (int p = tid; p < Npos; p += 256) {
        float a = bi;
        #pragma unroll 8
        for (int c = 0; c < CIN; ++c) a += wrow[c] * X[((long)b * CIN + c) * Npos + p];
        ybuf[p] = a; ls += a; lq += a * a;
    }
    #pragma unroll
    for (int m = 32; m; m >>= 1) { ls += __shfl_xor(ls, m); lq += __shfl_xor(lq, m); }
    const int lane = tid & 63, wid = tid >> 6;
    if (lane == 0) { rsum[wid] = ls; rsq[wid] = lq; }
    __syncthreads();
    if (tid == 0) {
        const float S  = rsum[0] + rsum[1] + rsum[2] + rsum[3];
        const float Q2 = rsq[0] + rsq[1] + rsq[2] + rsq[3];
        const float mu = S / Npos;
        const float var = Q2 / Npos - mu * mu;
        stats[0] = mu; stats[1] = rsqrtf(var + 1e-3f);
    }
    __syncthreads();
    const float k1 = stats[1] * sc[o];
    const float k2 = sh[o] - stats[0] * k1;
    for (int p = tid; p < Npos; p += 256)
        Y[((long)b * Cout + o) * Npos + p] = fmaxf(ybuf[p] * k1 + k2, 0.f);
}

// ---------------------------------------------------------------- final 4->1 conv -> logits
__global__ __launch_bounds__(256) void logits_kernel(
    const float* __restrict__ X, const float* __restrict__ W4, const float* __restrict__ b4,
    float* __restrict__ out, int Npos)
{
    const int idx = blockIdx.x * 256 + threadIdx.x;
    if (idx >= B_ * Npos) return;
    const int b = idx / Npos, n = idx % Npos;
    float acc = b4[0];
    #pragma unroll
    for (int c = 0; c < 4; ++c)
        acc += W4[c] * X[((long)b * 4 + c) * Npos + n];
    out[idx] = acc;
}

// ================================================================ host
extern "C" void kernel_launch(void* const* d_in, const int* in_sizes, int n_in,
                              void* d_out, int out_size, void* d_ws, size_t ws_size,
                              hipStream_t stream)
{
    const float* dX   = (const float*)d_in[1];
    const float* fpX  = (const float*)d_in[2];
    const float* lgin = (const float*)d_in[3];
    const float* Wq = (const float*)d_in[4];  const float* bq = (const float*)d_in[5];
    const float* Wk = (const float*)d_in[6];  const float* bk = (const float*)d_in[7];
    const float* Wv = (const float*)d_in[8];  const float* bv = (const float*)d_in[9];
    const float* Wm = (const float*)d_in[10]; const float* bm = (const float*)d_in[11];
    const float* Wc1= (const float*)d_in[12]; const float* bc1= (const float*)d_in[13];
    const float* bns= (const float*)d_in[14]; const float* bnsh=(const float*)d_in[15];
    const float* Wc2= (const float*)d_in[16]; const float* bc2= (const float*)d_in[17];
    const float* iW1= (const float*)d_in[18]; const float* ib1= (const float*)d_in[19];
    const float* s1 = (const float*)d_in[20]; const float* h1 = (const float*)d_in[21];
    const float* iW2= (const float*)d_in[22]; const float* ib2= (const float*)d_in[23];
    const float* s2 = (const float*)d_in[24]; const float* h2 = (const float*)d_in[25];
    const float* iW3= (const float*)d_in[26]; const float* ib3= (const float*)d_in[27];
    const float* s3 = (const float*)d_in[28]; const float* h3 = (const float*)d_in[29];
    const float* iW4= (const float*)d_in[30]; const float* ib4= (const float*)d_in[31];

    float* out_d      = (float*)d_out;                 // [2,128,6000]
    float* out_logits = out_d + (long)B_ * C_ * N_;    // [2,6000]

    float* f = (float*)d_ws;
    long off = 0;
    auto alloc = [&](long n) { float* p = f + off; off += n; return p; };
    float* featA = alloc((long)B_ * C_ * M_);
    float* featB = alloc((long)B_ * C_ * M_);
    float* qb    = alloc((long)B_ * C_ * N_);
    float* kb    = alloc((long)B_ * C_ * N_);
    float* vb    = alloc((long)B_ * C_ * N_);
    float* addb  = alloc((long)B_ * C_ * N_);
    float* xb    = alloc((long)B_ * C_ * N_);      // d_new - d_old
    float* x1raw = alloc((long)B_ * 64 * N_);
    float* x1b   = alloc((long)B_ * 64 * N_);
    float* x2b   = alloc((long)B_ * 16 * N_);
    float* x3b   = alloc((long)B_ * 4 * N_);
    float* psb   = alloc(2048);
    float* pqb   = alloc(2048);
    float* pmb   = alloc(200000);                  // >= B*H*KS*Nq max (192k)
    float* plb   = alloc(200000);
    float* big   = alloc(6200000);                 // pacc (<=6.144M) UNION hb (3.072M)
    float* pab = big;
    float* hb  = big;
    (void)ws_size; (void)in_sizes; (void)n_in; (void)out_size;

    auto conv = [&](int CIN, const float* Xa, const float* Xb, int csplit,
                    const float* W, const float* bias, const float* bsp, const float* bshp,
                    const float* resid, float* Yf, float* Yh,
                    int P, int Cout, int strideXa, int strideXb, int yfraw) {
        dim3 g((P + 63) / 64, Cout / 64, B_);
        if (CIN == 128)
            conv_kernel<128><<<g, 256, 0, stream>>>(Xa, Xb, W, bias, bsp, bshp, resid,
                                                    Yf, Yh, P, Cout, csplit, strideXa, strideXb, yfraw);
        else
            conv_kernel<256><<<g, 256, 0, stream>>>(Xa, Xb, W, bias, bsp, bshp, resid,
                                                    Yf, Yh, P, Cout, csplit, strideXa, strideXb, yfraw);
    };

    auto attn_layer = [&](const float* x1, const float* x2, int Nq, int Nk,
                          const float* maskl, int li, int KS, int chunkLen,
                          float* outF, float* outH, int yfraw) {
        const float* Wqi = Wq + (long)li * C_ * C_;     const float* bqi = bq + li * C_;
        const float* Wki = Wk + (long)li * C_ * C_;     const float* bki = bk + li * C_;
        const float* Wvi = Wv + (long)li * C_ * C_;     const float* bvi = bv + li * C_;
        const float* Wmi = Wm + (long)li * C_ * C_;     const float* bmi = bm + li * C_;
        const float* Wc1i= Wc1 + (long)li * 2*C_*2*C_;  const float* bc1i= bc1 + li * 2*C_;
        const float* bnsi= bns + li * 2*C_;             const float* bnshi= bnsh + li * 2*C_;
        const float* Wc2i= Wc2 + (long)li * C_ * 2*C_;  const float* bc2i= bc2 + li * C_;

        conv(128, x1, nullptr, 128, Wqi, bqi, nullptr, nullptr, nullptr, qb, nullptr, Nq, 128, C_*Nq, 0, 0);
        conv(128, x2, nullptr, 128, Wki, bki, nullptr, nullptr, nullptr, kb, nullptr, Nk, 128, C_*Nk, 0, 0);
        conv(128, x2, nullptr, 128, Wvi, bvi, nullptr, nullptr, nullptr, vb, nullptr, Nk, 128, C_*Nk, 0, 0);
        const int qblocks = (Nq + 255) / 256;
        attn_partial<<<dim3(qblocks, B_ * H_, KS), 256, 0, stream>>>(
            qb, kb, vb, maskl, pmb, plb, pab, Nq, Nk, KS, chunkLen);
        attn_combine<<<dim3(qblocks, B_ * H_, 4), 256, 0, stream>>>(
            pmb, plb, pab, addb, Nq, KS);
        conv(128, addb, nullptr, 128, Wmi, bmi, nullptr, nullptr, nullptr, qb, nullptr, Nq, 128, C_*Nq, 0, 0);
        conv(256, x1, qb, 128, Wc1i, bc1i, bnsi, bnshi, nullptr, hb, nullptr, Nq, 256, C_*Nq, C_*Nq, 0);
        conv(256, hb, nullptr, 256, Wc2i, bc2i, nullptr, nullptr, x1, outF, outH, Nq, 128, 2*C_*Nq, 0, yfraw);
    };

    // layer 0: feat = attn(feat_piece <- d, masked kv):  6qb*8*16 = 768 blocks, chunk 384
    attn_layer(fpX, dX, M_, N_, lgin, 0, 16, 384, featA, nullptr, 0);
    // layer 1: self-attn on feat:                        6qb*8*12 = 576 blocks, chunk 128
    attn_layer(featA, featA, M_, M_, nullptr, 1, 12, 128, featB, nullptr, 0);
    // layer 2: d_new = attn(d <- feat):                  24qb*8*4 = 768 blocks, chunk 384
    attn_layer(dX, featB, N_, M_, nullptr, 2, 4, 384, xb, out_d, 1);

    // instance-norm stack: first (128->64) via GEMM conv + split-stats; tail fused
    conv(128, xb, nullptr, 128, iW1, ib1, nullptr, nullptr, nullptr, x1raw, nullptr, N_, 64, C_*N_, 0, 0);
    inorm_stats<6><<<dim3(64, B_, 6), 256, 0, stream>>>(x1raw, psb, pqb, 64, N_);
    inorm_norm<6> <<<dim3(64, B_, 6), 256, 0, stream>>>(x1raw, psb, pqb, s1, h1, x1b, 64, N_);
    inorm_kernel<64><<<dim3(16, B_), 256, 0, stream>>>(x1b, iW2, ib2, s2, h2, x2b, N_);
    inorm_kernel<16><<<dim3(4,  B_), 256, 0, stream>>>(x2b, iW3, ib3, s3, h3, x3b, N_);
    logits_kernel<<<dim3((B_ * N_ + 255) / 256), 256, 0, stream>>>(x3b, iW4, ib4, out_logits, N_);
}

// Round 4
// 729.937 us; speedup vs baseline: 1.6199x; 1.2721x over previous
//
#include <hip/hip_runtime.h>
#include <math.h>

#define B_  2
#define C_  128
#define N_  6000
#define M_  1500
#define H_  4
#define DH_ 32

typedef __attribute__((ext_vector_type(8))) short bf16x8;   // 8 bf16 = 4 VGPRs
typedef __attribute__((ext_vector_type(4))) float f32x4;

static __device__ __forceinline__ unsigned short f2bf(float x) {
    unsigned u = __float_as_uint(x);
    return (unsigned short)((u + 0x7fffu + ((u >> 16) & 1u)) >> 16);   // RNE
}

// ---------------------------------------------------------------- conv1 (GEMM)
template<int CIN>
__global__ __launch_bounds__(256) void conv_kernel(
    const float* __restrict__ Xa, const float* __restrict__ Xb,
    const float* __restrict__ W, const float* __restrict__ bias,
    const float* __restrict__ bs, const float* __restrict__ bsh,
    const float* __restrict__ resid,
    float* __restrict__ Yf, float* __restrict__ Yh,
    int P, int Cout, int csplit, int strideXa, int strideXb, int yfraw)
{
    constexpr int CK = 16;
    __shared__ alignas(16) float Xs[CK][64];
    __shared__ alignas(16) float Ws[CK][68];
    const int tid = threadIdx.x;
    const int tx = tid & 15, ty = tid >> 4;
    const int b  = blockIdx.z;
    const int o0 = blockIdx.y * 64;
    const int p0 = blockIdx.x * 64;
    float acc[4][4] = {};
    const long offA = (long)b * strideXa;
    const long offB = (long)b * strideXb;

    for (int cc = 0; cc < CIN; cc += CK) {
        #pragma unroll
        for (int i = 0; i < 4; ++i) {
            int e = tid + 256 * i;
            int c = e >> 6, j = e & 63;
            int ch = cc + c;
            int pp = p0 + j; if (pp >= P) pp = P - 1;
            float v = (ch < csplit) ? Xa[offA + (long)ch * P + pp]
                                    : Xb[offB + (long)(ch - csplit) * P + pp];
            Xs[c][j] = v;
        }
        #pragma unroll
        for (int i = 0; i < 4; ++i) {
            int e = tid + 256 * i;
            int o = e >> 4, c = e & 15;
            Ws[c][o] = W[(long)(o0 + o) * CIN + cc + c];
        }
        __syncthreads();
        #pragma unroll
        for (int kk = 0; kk < CK; ++kk) {
            const float4 wv = *(const float4*)&Ws[kk][ty * 4];
            const float4 xv = *(const float4*)&Xs[kk][tx * 4];
            const float w[4] = {wv.x, wv.y, wv.z, wv.w};
            const float x[4] = {xv.x, xv.y, xv.z, xv.w};
            #pragma unroll
            for (int i = 0; i < 4; ++i)
                #pragma unroll
                for (int j = 0; j < 4; ++j)
                    acc[i][j] += w[i] * x[j];
        }
        __syncthreads();
    }

    const long strideY = (long)Cout * P;
    #pragma unroll
    for (int i = 0; i < 4; ++i) {
        const int o = o0 + ty * 4 + i;
        const float bi = bias[o];
        float sv = 0.f, shv = 0.f;
        if (bs) { sv = bs[o]; shv = bsh[o]; }
        #pragma unroll
        for (int j = 0; j < 4; ++j) {
            const int p = p0 + tx * 4 + j;
            if (p < P) {
                float v = acc[i][j] + bi;
                if (bs) v = fmaxf(v * sv + shv, 0.f);
                float fin = v;
                const long idx = (long)b * strideY + (long)o * P + p;
                if (resid) fin += resid[idx];
                if (Yf) Yf[idx] = yfraw ? v : fin;
                if (Yh) Yh[idx] = fin;
            }
        }
    }
}

// ---------------------------------------------------------------- flash attention (MFMA, partials)
// Block = 4 waves; wave owns 16 queries (q0..q0+15). 64-key tiles via mfma_f32_16x16x32_bf16.
// QK: A = Q[m=q(lane&15)][k=dh(quad*8+j)], B = Ks[key][dh].  S in C-layout:
// lane holds S[q=quad*4+r][key=kg*16+(lane&15)], kg=0..3.  Online softmax per C-layout row.
// P -> LDS (C-layout write) -> A-layout read -> PV with B = Vs[dh][key].
__global__ __launch_bounds__(256) void attn_partial(
    const float* __restrict__ Q, const float* __restrict__ K, const float* __restrict__ V,
    const float* __restrict__ lgin,     // null -> no kv mask
    float* __restrict__ pm, float* __restrict__ pl, float* __restrict__ pacc,
    int Nq, int Nk, int KS, int chunkLen)
{
    __shared__ alignas(16) unsigned short Ks[64][40];   // [key][dh], row 80B: b128 reads 2-way
    __shared__ alignas(16) unsigned short Vs[32][72];   // [dh][key], row 144B: b128 reads 2-way
    __shared__ alignas(16) unsigned short Ps[4][16][72]; // per-wave P round-trip
    __shared__ float biasS[64];

    const int tid  = threadIdx.x;
    const int wave = tid >> 6, lane = tid & 63;
    const int l15  = lane & 15, quad = lane >> 4;
    const int bh = blockIdx.y, b = bh >> 2, h = bh & 3;
    const int split = blockIdx.z;
    const int q0 = blockIdx.x * 64 + wave * 16;

    const long qoff = ((long)b * C_ + h * DH_) * Nq;
    const long koff = ((long)b * C_ + h * DH_) * Nk;
    const float invs = 0.17677669529663687f;   // 1/sqrt(32)

    // Q A-fragment: A[m=l15][k=quad*8+j]
    bf16x8 qa;
    {
        int qq = q0 + l15; if (qq >= Nq) qq = Nq - 1;
        #pragma unroll
        for (int j = 0; j < 8; ++j)
            qa[j] = (short)f2bf(Q[qoff + (long)(quad * 8 + j) * Nq + qq]);
    }

    float m_i[4] = {-INFINITY, -INFINITY, -INFINITY, -INFINITY};
    float lp[4]  = {0.f, 0.f, 0.f, 0.f};
    f32x4 o0 = {0.f, 0.f, 0.f, 0.f}, o1 = {0.f, 0.f, 0.f, 0.f};

    const int kbeg = split * chunkLen;
    const int kend = min(Nk, kbeg + chunkLen);
    const int key2 = tid & 31, di = tid >> 5;   // staging: keys {2*key2,2*key2+1}, dh group di

    for (int m0 = kbeg; m0 < kend; m0 += 64) {
        __syncthreads();                         // protect Ks/Vs from prior-iter PV readers
        if (tid < 64) {
            int mm = m0 + tid;
            float bv = -1e30f;                   // out-of-range key
            if (mm < kend) bv = (lgin && !(lgin[(long)b * Nk + mm] > 0.f)) ? -1e6f : 0.f;
            biasS[tid] = bv;
        }
        {
            int kA = m0 + 2 * key2;
            int kAc = kA < Nk ? kA : Nk - 1;
            int kBc = kA + 1 < Nk ? kA + 1 : Nk - 1;
            #pragma unroll
            for (int i = 0; i < 4; ++i) {
                int d = di * 4 + i;
                const float* kp = &K[koff + (long)d * Nk];
                const float* vp = &V[koff + (long)d * Nk];
                float kx, ky, vx, vy;
                if (kA + 1 < Nk) {
                    float2 t2 = *(const float2*)&kp[kA]; kx = t2.x; ky = t2.y;
                    float2 t3 = *(const float2*)&vp[kA]; vx = t3.x; vy = t3.y;
                } else { kx = kp[kAc]; ky = kp[kBc]; vx = vp[kAc]; vy = vp[kBc]; }
                Ks[2 * key2][d]     = f2bf(kx);
                Ks[2 * key2 + 1][d] = f2bf(ky);
                *(unsigned*)&Vs[d][2 * key2] =
                    (unsigned)f2bf(vx) | ((unsigned)f2bf(vy) << 16);
            }
        }
        __syncthreads();

        // ---- QK: 4 mfmas (key groups of 16)
        f32x4 sacc[4];
        #pragma unroll
        for (int kg = 0; kg < 4; ++kg) {
            sacc[kg] = (f32x4){0.f, 0.f, 0.f, 0.f};
            bf16x8 kb_ = *(const bf16x8*)&Ks[kg * 16 + l15][quad * 8];
            sacc[kg] = __builtin_amdgcn_mfma_f32_16x16x32_bf16(qa, kb_, sacc[kg], 0, 0, 0);
        }

        // ---- online softmax in C-layout
        float s[4][4], mx[4];
        #pragma unroll
        for (int kg = 0; kg < 4; ++kg) {
            const float bv = biasS[kg * 16 + l15];
            #pragma unroll
            for (int r = 0; r < 4; ++r) s[kg][r] = (sacc[kg][r] + bv) * invs;
        }
        #pragma unroll
        for (int r = 0; r < 4; ++r)
            mx[r] = fmaxf(fmaxf(s[0][r], s[1][r]), fmaxf(s[2][r], s[3][r]));
        #pragma unroll
        for (int mk = 1; mk < 16; mk <<= 1)
            #pragma unroll
            for (int r = 0; r < 4; ++r)
                mx[r] = fmaxf(mx[r], __shfl_xor(mx[r], mk));
        float cor[4];
        #pragma unroll
        for (int r = 0; r < 4; ++r) {
            const float mn = fmaxf(m_i[r], mx[r]);
            cor[r] = __expf(m_i[r] - mn);
            m_i[r] = mn;
            lp[r] *= cor[r];
        }
        #pragma unroll
        for (int kg = 0; kg < 4; ++kg)
            #pragma unroll
            for (int r = 0; r < 4; ++r) {
                const float pj = __expf(s[kg][r] - m_i[r]);
                lp[r] += pj;
                Ps[wave][quad * 4 + r][kg * 16 + l15] = f2bf(pj);
            }
        #pragma unroll
        for (int r = 0; r < 4; ++r) { o0[r] *= cor[r]; o1[r] *= cor[r]; }
        __syncthreads();                          // Ps visible (wave-local lgkm drain)

        // ---- PV: 4 mfmas (2 key-groups of 32 x 2 dh-groups of 16)
        bf16x8 pa0 = *(const bf16x8*)&Ps[wave][l15][quad * 8];
        bf16x8 pa1 = *(const bf16x8*)&Ps[wave][l15][32 + quad * 8];
        bf16x8 vb00 = *(const bf16x8*)&Vs[l15][quad * 8];
        bf16x8 vb01 = *(const bf16x8*)&Vs[16 + l15][quad * 8];
        bf16x8 vb10 = *(const bf16x8*)&Vs[l15][32 + quad * 8];
        bf16x8 vb11 = *(const bf16x8*)&Vs[16 + l15][32 + quad * 8];
        o0 = __builtin_amdgcn_mfma_f32_16x16x32_bf16(pa0, vb00, o0, 0, 0, 0);
        o0 = __builtin_amdgcn_mfma_f32_16x16x32_bf16(pa1, vb10, o0, 0, 0, 0);
        o1 = __builtin_amdgcn_mfma_f32_16x16x32_bf16(pa0, vb01, o1, 0, 0, 0);
        o1 = __builtin_amdgcn_mfma_f32_16x16x32_bf16(pa1, vb11, o1, 0, 0, 0);
    }

    // final cross-lane l reduction (over the 16 key-lanes of the quad)
    #pragma unroll
    for (int mk = 1; mk < 16; mk <<= 1)
        #pragma unroll
        for (int r = 0; r < 4; ++r) lp[r] += __shfl_xor(lp[r], mk);

    const long base = (long)bh * KS + split;
    #pragma unroll
    for (int r = 0; r < 4; ++r) {
        const int pq = q0 + quad * 4 + r;
        if (pq < Nq) {
            if (l15 == 0) { pm[base * Nq + pq] = m_i[r]; pl[base * Nq + pq] = lp[r]; }
            pacc[(base * 32 + l15) * Nq + pq]      = o0[r];
            pacc[(base * 32 + 16 + l15) * Nq + pq] = o1[r];
        }
    }
}

// ---------------------------------------------------------------- combine splits (8 dims/block-z)
__global__ __launch_bounds__(256) void attn_combine(
    const float* __restrict__ pm, const float* __restrict__ pl, const float* __restrict__ pacc,
    float* __restrict__ OUT, int Nq, int KS)
{
    const int tid = threadIdx.x;
    const int bh = blockIdx.y, b = bh >> 2, h = bh & 3;
    const int d0 = blockIdx.z * 8;
    const int p = blockIdx.x * 256 + tid;
    if (p >= Nq) return;
    float mg = -INFINITY;
    for (int s = 0; s < KS; ++s) mg = fmaxf(mg, pm[((long)bh * KS + s) * Nq + p]);
    float acc[8];
    #pragma unroll
    for (int d = 0; d < 8; ++d) acc[d] = 0.f;
    float lg = 0.f;
    for (int s = 0; s < KS; ++s) {
        const long base = (long)bh * KS + s;
        const float w = __expf(pm[base * Nq + p] - mg);
        lg += pl[base * Nq + p] * w;
        #pragma unroll
        for (int d = 0; d < 8; ++d) acc[d] += pacc[(base * 32 + d0 + d) * Nq + p] * w;
    }
    const float inv = 1.f / lg;
    #pragma unroll
    for (int d = 0; d < 8; ++d)
        OUT[((long)b * C_ + h * DH_ + d0 + d) * Nq + p] = acc[d] * inv;
}

// ---------------------------------------------------------------- inorm split stats + normalize
template<int SPLITS>
__global__ __launch_bounds__(256) void inorm_stats(
    const float* __restrict__ Y, float* __restrict__ ps, float* __restrict__ pq,
    int Cout, int Npos)
{
    __shared__ float rsum[4], rsq[4];
    const int tid = threadIdx.x;
    const int o = blockIdx.x, b = blockIdx.y, s = blockIdx.z;
    const int chunk = (Npos + SPLITS - 1) / SPLITS;
    const int pbeg = s * chunk, pend = min(Npos, pbeg + chunk);
    const float* src = Y + ((long)b * Cout + o) * Npos;
    float ls = 0.f, lq = 0.f;
    for (int p = pbeg + tid; p < pend; p += 256) { float a = src[p]; ls += a; lq += a * a; }
    #pragma unroll
    for (int m = 32; m; m >>= 1) { ls += __shfl_xor(ls, m); lq += __shfl_xor(lq, m); }
    const int lane = tid & 63, wid = tid >> 6;
    if (lane == 0) { rsum[wid] = ls; rsq[wid] = lq; }
    __syncthreads();
    if (tid == 0) {
        ps[((long)b * Cout + o) * SPLITS + s] = rsum[0] + rsum[1] + rsum[2] + rsum[3];
        pq[((long)b * Cout + o) * SPLITS + s] = rsq[0] + rsq[1] + rsq[2] + rsq[3];
    }
}

template<int SPLITS>
__global__ __launch_bounds__(256) void inorm_norm(
    const float* __restrict__ Y, const float* __restrict__ ps, const float* __restrict__ pq,
    const float* __restrict__ sc, const float* __restrict__ sh,
    float* __restrict__ OUT, int Cout, int Npos)
{
    const int tid = threadIdx.x;
    const int o = blockIdx.x, b = blockIdx.y, s = blockIdx.z;
    float S = 0.f, Q2 = 0.f;
    #pragma unroll
    for (int i = 0; i < SPLITS; ++i) {
        S  += ps[((long)b * Cout + o) * SPLITS + i];
        Q2 += pq[((long)b * Cout + o) * SPLITS + i];
    }
    const float mu = S / Npos;
    const float var = Q2 / Npos - mu * mu;
    const float rs = rsqrtf(var + 1e-3f);
    const float k1 = rs * sc[o];
    const float k2 = sh[o] - mu * k1;
    const int chunk = (Npos + SPLITS - 1) / SPLITS;
    const int pbeg = s * chunk, pend = min(Npos, pbeg + chunk);
    const float* src = Y + ((long)b * Cout + o) * Npos;
    float* dst = OUT + ((long)b * Cout + o) * Npos;
    for (int p = pbeg + tid; p < pend; p += 256)
        dst[p] = fmaxf(src[p] * k1 + k2, 0.f);
}

// ---------------------------------------------------------------- fused conv+inorm (small tail convs)
template<int CIN>
__global__ __launch_bounds__(256) void inorm_kernel(
    const float* __restrict__ X, const float* __restrict__ W, const float* __restrict__ bias,
    const float* __restrict__ sc, const float* __restrict__ sh,
    float* __restrict__ Y, int Npos)
{
    __shared__ float wrow[CIN];
    __shared__ float ybuf[N_];
    __shared__ float rsum[4], rsq[4], stats[2];
    const int tid = threadIdx.x;
    const int o = blockIdx.x, b = blockIdx.y, Cout = gridDim.x;
    for (int c = tid; c < CIN; c += 256) wrow[c] = W[o * CIN + c];
    __syncthreads();
    const float bi = bias[o];
    float ls = 0.f, lq = 0.f;
    for (int p = tid; p < Npos; p += 256) {
        float a = bi;
        #pragma unroll 8
        for (int c = 0; c < CIN; ++c) a += wrow[c] * X[((long)b * CIN + c) * Npos + p];
        ybuf[p] = a; ls += a; lq += a * a;
    }
    #pragma unroll
    for (int m = 32; m; m >>= 1) { ls += __shfl_xor(ls, m); lq += __shfl_xor(lq, m); }
    const int lane = tid & 63, wid = tid >> 6;
    if (lane == 0) { rsum[wid] = ls; rsq[wid] = lq; }
    __syncthreads();
    if (tid == 0) {
        const float S  = rsum[0] + rsum[1] + rsum[2] + rsum[3];
        const float Q2 = rsq[0] + rsq[1] + rsq[2] + rsq[3];
        const float mu = S / Npos;
        const float var = Q2 / Npos - mu * mu;
        stats[0] = mu; stats[1] = rsqrtf(var + 1e-3f);
    }
    __syncthreads();
    const float k1 = stats[1] * sc[o];
    const float k2 = sh[o] - stats[0] * k1;
    for (int p = tid; p < Npos; p += 256)
        Y[((long)b * Cout + o) * Npos + p] = fmaxf(ybuf[p] * k1 + k2, 0.f);
}

// ---------------------------------------------------------------- final 4->1 conv -> logits
__global__ __launch_bounds__(256) void logits_kernel(
    const float* __restrict__ X, const float* __restrict__ W4, const float* __restrict__ b4,
    float* __restrict__ out, int Npos)
{
    const int idx = blockIdx.x * 256 + threadIdx.x;
    if (idx >= B_ * Npos) return;
    const int b = idx / Npos, n = idx % Npos;
    float acc = b4[0];
    #pragma unroll
    for (int c = 0; c < 4; ++c)
        acc += W4[c] * X[((long)b * 4 + c) * Npos + n];
    out[idx] = acc;
}

// ================================================================ host
extern "C" void kernel_launch(void* const* d_in, const int* in_sizes, int n_in,
                              void* d_out, int out_size, void* d_ws, size_t ws_size,
                              hipStream_t stream)
{
    const float* dX   = (const float*)d_in[1];
    const float* fpX  = (const float*)d_in[2];
    const float* lgin = (const float*)d_in[3];
    const float* Wq = (const float*)d_in[4];  const float* bq = (const float*)d_in[5];
    const float* Wk = (const float*)d_in[6];  const float* bk = (const float*)d_in[7];
    const float* Wv = (const float*)d_in[8];  const float* bv = (const float*)d_in[9];
    const float* Wm = (const float*)d_in[10]; const float* bm = (const float*)d_in[11];
    const float* Wc1= (const float*)d_in[12]; const float* bc1= (const float*)d_in[13];
    const float* bns= (const float*)d_in[14]; const float* bnsh=(const float*)d_in[15];
    const float* Wc2= (const float*)d_in[16]; const float* bc2= (const float*)d_in[17];
    const float* iW1= (const float*)d_in[18]; const float* ib1= (const float*)d_in[19];
    const float* s1 = (const float*)d_in[20]; const float* h1 = (const float*)d_in[21];
    const float* iW2= (const float*)d_in[22]; const float* ib2= (const float*)d_in[23];
    const float* s2 = (const float*)d_in[24]; const float* h2 = (const float*)d_in[25];
    const float* iW3= (const float*)d_in[26]; const float* ib3= (const float*)d_in[27];
    const float* s3 = (const float*)d_in[28]; const float* h3 = (const float*)d_in[29];
    const float* iW4= (const float*)d_in[30]; const float* ib4= (const float*)d_in[31];

    float* out_d      = (float*)d_out;                 // [2,128,6000]
    float* out_logits = out_d + (long)B_ * C_ * N_;    // [2,6000]

    float* f = (float*)d_ws;
    long off = 0;
    auto alloc = [&](long n) { float* p = f + off; off += n; return p; };
    float* featA = alloc((long)B_ * C_ * M_);
    float* featB = alloc((long)B_ * C_ * M_);
    float* qb    = alloc((long)B_ * C_ * N_);
    float* kb    = alloc((long)B_ * C_ * N_);
    float* vb    = alloc((long)B_ * C_ * N_);
    float* addb  = alloc((long)B_ * C_ * N_);
    float* xb    = alloc((long)B_ * C_ * N_);
    float* x1raw = alloc((long)B_ * 64 * N_);
    float* x1b   = alloc((long)B_ * 64 * N_);
    float* x2b   = alloc((long)B_ * 16 * N_);
    float* x3b   = alloc((long)B_ * 4 * N_);
    float* psb   = alloc(2048);
    float* pqb   = alloc(2048);
    float* pmb   = alloc(200000);
    float* plb   = alloc(200000);
    float* big   = alloc(6200000);                 // pacc UNION hb (disjoint lifetimes)
    float* pab = big;
    float* hb  = big;
    (void)ws_size; (void)in_sizes; (void)n_in; (void)out_size;

    auto conv = [&](int CIN, const float* Xa, const float* Xb, int csplit,
                    const float* W, const float* bias, const float* bsp, const float* bshp,
                    const float* resid, float* Yf, float* Yh,
                    int P, int Cout, int strideXa, int strideXb, int yfraw) {
        dim3 g((P + 63) / 64, Cout / 64, B_);
        if (CIN == 128)
            conv_kernel<128><<<g, 256, 0, stream>>>(Xa, Xb, W, bias, bsp, bshp, resid,
                                                    Yf, Yh, P, Cout, csplit, strideXa, strideXb, yfraw);
        else
            conv_kernel<256><<<g, 256, 0, stream>>>(Xa, Xb, W, bias, bsp, bshp, resid,
                                                    Yf, Yh, P, Cout, csplit, strideXa, strideXb, yfraw);
    };

    auto attn_layer = [&](const float* x1, const float* x2, int Nq, int Nk,
                          const float* maskl, int li, int KS, int chunkLen,
                          float* outF, float* outH, int yfraw) {
        const float* Wqi = Wq + (long)li * C_ * C_;     const float* bqi = bq + li * C_;
        const float* Wki = Wk + (long)li * C_ * C_;     const float* bki = bk + li * C_;
        const float* Wvi = Wv + (long)li * C_ * C_;     const float* bvi = bv + li * C_;
        const float* Wmi = Wm + (long)li * C_ * C_;     const float* bmi = bm + li * C_;
        const float* Wc1i= Wc1 + (long)li * 2*C_*2*C_;  const float* bc1i= bc1 + li * 2*C_;
        const float* bnsi= bns + li * 2*C_;             const float* bnshi= bnsh + li * 2*C_;
        const float* Wc2i= Wc2 + (long)li * C_ * 2*C_;  const float* bc2i= bc2 + li * C_;

        conv(128, x1, nullptr, 128, Wqi, bqi, nullptr, nullptr, nullptr, qb, nullptr, Nq, 128, C_*Nq, 0, 0);
        conv(128, x2, nullptr, 128, Wki, bki, nullptr, nullptr, nullptr, kb, nullptr, Nk, 128, C_*Nk, 0, 0);
        conv(128, x2, nullptr, 128, Wvi, bvi, nullptr, nullptr, nullptr, vb, nullptr, Nk, 128, C_*Nk, 0, 0);
        attn_partial<<<dim3((Nq + 63) / 64, B_ * H_, KS), 256, 0, stream>>>(
            qb, kb, vb, maskl, pmb, plb, pab, Nq, Nk, KS, chunkLen);
        attn_combine<<<dim3((Nq + 255) / 256, B_ * H_, 4), 256, 0, stream>>>(
            pmb, plb, pab, addb, Nq, KS);
        conv(128, addb, nullptr, 128, Wmi, bmi, nullptr, nullptr, nullptr, qb, nullptr, Nq, 128, C_*Nq, 0, 0);
        conv(256, x1, qb, 128, Wc1i, bc1i, bnsi, bnshi, nullptr, hb, nullptr, Nq, 256, C_*Nq, C_*Nq, 0);
        conv(256, hb, nullptr, 256, Wc2i, bc2i, nullptr, nullptr, x1, outF, outH, Nq, 128, 2*C_*Nq, 0, yfraw);
    };

    // layer 0: feat = attn(feat_piece <- d, masked kv): 24qb*8*4 = 768 blocks, chunk 1536
    attn_layer(fpX, dX, M_, N_, lgin, 0, 4, 1536, featA, nullptr, 0);
    // layer 1: self-attn on feat:                       24qb*8*2 = 384 blocks, chunk 768
    attn_layer(featA, featA, M_, M_, nullptr, 1, 2, 768, featB, nullptr, 0);
    // layer 2: d_new = attn(d <- feat):                 94qb*8*1 = 752 blocks, chunk 1504
    attn_layer(dX, featB, N_, M_, nullptr, 2, 1, 1504, xb, out_d, 1);

    // instance-norm stack
    conv(128, xb, nullptr, 128, iW1, ib1, nullptr, nullptr, nullptr, x1raw, nullptr, N_, 64, C_*N_, 0, 0);
    inorm_stats<6><<<dim3(64, B_, 6), 256, 0, stream>>>(x1raw, psb, pqb, 64, N_);
    inorm_norm<6> <<<dim3(64, B_, 6), 256, 0, stream>>>(x1raw, psb, pqb, s1, h1, x1b, 64, N_);
    inorm_kernel<64><<<dim3(16, B_), 256, 0, stream>>>(x1b, iW2, ib2, s2, h2, x2b, N_);
    inorm_kernel<16><<<dim3(4,  B_), 256, 0, stream>>>(x2b, iW3, ib3, s3, h3, x3b, N_);
    logits_kernel<<<dim3((B_ * N_ + 255) / 256), 256, 0, stream>>>(x3b, iW4, ib4, out_logits, N_);
}

// Round 5
// 469.443 us; speedup vs baseline: 2.5189x; 1.5549x over previous
//
#include <hip/hip_runtime.h>
#include <math.h>

#define B_  2
#define C_  128
#define N_  6000
#define M_  1500
#define H_  4
#define DH_ 32

typedef __attribute__((ext_vector_type(8))) short bf16x8;   // 8 bf16 = 4 VGPRs
typedef __attribute__((ext_vector_type(4))) float f32x4;
typedef unsigned short u16;

static __device__ __forceinline__ u16 f2bf(float x) {
    unsigned u = __float_as_uint(x);
    return (u16)((u + 0x7fffu + ((u >> 16) & 1u)) >> 16);   // RNE
}
#define MFMA(a,b,c) __builtin_amdgcn_mfma_f32_16x16x32_bf16((a),(b),(c),0,0,0)
// exp2-domain softmax: scores scaled by invs*log2(e), exp via exp2f (v_exp_f32)
#define INVS2 (0.17677669529663687f * 1.4426950408889634f)

// ---------------------------------------------------------------- prep: weights->bf16, zero stats
__global__ __launch_bounds__(256) void prep_kernel(
    const float* __restrict__ Wq, const float* __restrict__ Wk, const float* __restrict__ Wv,
    const float* __restrict__ Wm, const float* __restrict__ Wc1, const float* __restrict__ Wc2,
    const float* __restrict__ iW1,
    u16* __restrict__ wq, u16* __restrict__ wk, u16* __restrict__ wv, u16* __restrict__ wm,
    u16* __restrict__ wc1, u16* __restrict__ wc2, u16* __restrict__ w1,
    float* __restrict__ zstats)
{
    long i = (long)blockIdx.x * 256 + threadIdx.x;
    if (i < 512)    zstats[i] = 0.f;
    if (i < 49152)  { wq[i] = f2bf(Wq[i]); wk[i] = f2bf(Wk[i]);
                      wv[i] = f2bf(Wv[i]); wm[i] = f2bf(Wm[i]); }
    if (i < 196608) wc1[i] = f2bf(Wc1[i]);
    if (i < 98304)  wc2[i] = f2bf(Wc2[i]);
    if (i < 8192)   w1[i]  = f2bf(iW1[i]);
}

// ---------------------------------------------------------------- fused q/k/v conv (MFMA, CIN=128)
// grid: x = pos-tile(64), y = job*2+otile (job 0:q 1:k 2:v), z = b
__global__ __launch_bounds__(256) void qkv_kernel(
    const float* __restrict__ x1, const float* __restrict__ x2, int Pq, int Pk,
    const u16* __restrict__ wq, const u16* __restrict__ wk, const u16* __restrict__ wv,
    const float* __restrict__ bq, const float* __restrict__ bk, const float* __restrict__ bv,
    float* __restrict__ qb, float* __restrict__ kb, float* __restrict__ vb)
{
    __shared__ u16 Xt[64][40];      // [pos][cin-chunk], row 80B
    const int tid = threadIdx.x;
    const int wid = tid >> 6, lane = tid & 63;
    const int l15 = lane & 15, quad = lane >> 4;
    const int job = blockIdx.y >> 1, ot = blockIdx.y & 1;
    const int b = blockIdx.z;
    const int p0 = blockIdx.x * 64;
    const float* X; const u16* W; const float* bias; float* Y; int P;
    if (job == 0)      { X = x1; W = wq; bias = bq; Y = qb; P = Pq; }
    else if (job == 1) { X = x2; W = wk; bias = bk; Y = kb; P = Pk; }
    else               { X = x2; W = wv; bias = bv; Y = vb; P = Pk; }
    if (p0 >= P) return;
    const long xoff = (long)b * C_ * P;
    const int sp = tid & 63, cg = tid >> 6;
    f32x4 acc[4] = {};

    for (int k0 = 0; k0 < 128; k0 += 32) {
        bf16x8 st;
        {
            const int pp = (p0 + sp < P) ? p0 + sp : P - 1;
            #pragma unroll
            for (int j = 0; j < 8; ++j)
                st[j] = (short)f2bf(X[xoff + (long)(k0 + cg * 8 + j) * P + pp]);
        }
        __syncthreads();
        *(bf16x8*)&Xt[sp][cg * 8] = st;
        __syncthreads();
        const bf16x8 af = *(const bf16x8*)(W + (long)(ot * 64 + wid * 16 + l15) * 128 + k0 + quad * 8);
        #pragma unroll
        for (int pg = 0; pg < 4; ++pg) {
            const bf16x8 bfr = *(const bf16x8*)&Xt[pg * 16 + l15][quad * 8];
            acc[pg] = MFMA(af, bfr, acc[pg]);
        }
    }
    #pragma unroll
    for (int pg = 0; pg < 4; ++pg)
        #pragma unroll
        for (int r = 0; r < 4; ++r) {
            const int o = ot * 64 + wid * 16 + quad * 4 + r;
            const int p = p0 + pg * 16 + l15;
            if (p < P) Y[((long)b * 128 + o) * P + p] = acc[pg][r] + bias[o];
        }
}

// ---------------------------------------------------------------- flash attention (MFMA, partials)
__global__ __launch_bounds__(256) void attn_partial(
    const float* __restrict__ Q, const float* __restrict__ K, const float* __restrict__ V,
    const float* __restrict__ lgin,
    float* __restrict__ pm, float* __restrict__ pl, float* __restrict__ pacc,
    int Nq, int Nk, int KS, int chunkLen)
{
    __shared__ u16 Ks[64][40];     // [key][dh]
    __shared__ u16 Vs[32][72];     // [dh][key]
    __shared__ u16 Ps[4][16][72];  // per-wave P round-trip
    __shared__ float biasS[64];

    const int tid  = threadIdx.x;
    const int wave = tid >> 6, lane = tid & 63;
    const int l15  = lane & 15, quad = lane >> 4;
    const int bh = blockIdx.y, b = bh >> 2, h = bh & 3;
    const int split = blockIdx.z;
    const int q0 = blockIdx.x * 64 + wave * 16;

    const long qoff = ((long)b * C_ + h * DH_) * Nq;
    const long koff = ((long)b * C_ + h * DH_) * Nk;

    bf16x8 qa;
    {
        int qq = q0 + l15; if (qq >= Nq) qq = Nq - 1;
        #pragma unroll
        for (int j = 0; j < 8; ++j)
            qa[j] = (short)f2bf(Q[qoff + (long)(quad * 8 + j) * Nq + qq]);
    }

    float m_i[4] = {-INFINITY, -INFINITY, -INFINITY, -INFINITY};
    float lp[4]  = {0.f, 0.f, 0.f, 0.f};
    f32x4 o0 = {0.f, 0.f, 0.f, 0.f}, o1 = {0.f, 0.f, 0.f, 0.f};

    const int kbeg = split * chunkLen;
    const int kend = min(Nk, kbeg + chunkLen);
    const int kkey = tid & 63, dg = tid >> 6;   // K staging: per-key b128 along dh
    const int key2 = tid & 31, dv = tid >> 5;   // V staging: key-pair u32 writes

    for (int m0 = kbeg; m0 < kend; m0 += 64) {
        __syncthreads();
        if (tid < 64) {
            int mm = m0 + tid;
            float bv = -1e30f;
            if (mm < kend) bv = (lgin && !(lgin[(long)b * Nk + mm] > 0.f)) ? -1e6f : 0.f;
            biasS[tid] = bv;
        }
        {   // K: thread owns one key, 8 dh values -> one ds_write_b128 (conflict-free phases)
            int mm = m0 + kkey; int mmc = mm < Nk ? mm : Nk - 1;
            bf16x8 kr;
            #pragma unroll
            for (int j = 0; j < 8; ++j)
                kr[j] = (short)f2bf(K[koff + (long)(dg * 8 + j) * Nk + mmc]);
            *(bf16x8*)&Ks[kkey][dg * 8] = kr;
        }
        {   // V: float2 along keys -> u32 writes (conflict-free)
            int kA = m0 + 2 * key2;
            int kAc = kA < Nk ? kA : Nk - 1;
            int kBc = kA + 1 < Nk ? kA + 1 : Nk - 1;
            #pragma unroll
            for (int i = 0; i < 4; ++i) {
                int d = dv * 4 + i;
                const float* vp = &V[koff + (long)d * Nk];
                float vx, vy;
                if (kA + 1 < Nk) { float2 t = *(const float2*)&vp[kA]; vx = t.x; vy = t.y; }
                else             { vx = vp[kAc]; vy = vp[kBc]; }
                *(unsigned*)&Vs[d][2 * key2] = (unsigned)f2bf(vx) | ((unsigned)f2bf(vy) << 16);
            }
        }
        __syncthreads();

        f32x4 sacc[4];
        #pragma unroll
        for (int kg = 0; kg < 4; ++kg) {
            sacc[kg] = (f32x4){0.f, 0.f, 0.f, 0.f};
            const bf16x8 kb_ = *(const bf16x8*)&Ks[kg * 16 + l15][quad * 8];
            sacc[kg] = MFMA(qa, kb_, sacc[kg]);
        }

        float s[4][4], mx[4];
        #pragma unroll
        for (int kg = 0; kg < 4; ++kg) {
            const float bv = biasS[kg * 16 + l15];
            #pragma unroll
            for (int r = 0; r < 4; ++r) s[kg][r] = (sacc[kg][r] + bv) * INVS2;
        }
        #pragma unroll
        for (int r = 0; r < 4; ++r)
            mx[r] = fmaxf(fmaxf(s[0][r], s[1][r]), fmaxf(s[2][r], s[3][r]));
        #pragma unroll
        for (int mk = 1; mk < 16; mk <<= 1)
            #pragma unroll
            for (int r = 0; r < 4; ++r)
                mx[r] = fmaxf(mx[r], __shfl_xor(mx[r], mk));
        float cor[4];
        #pragma unroll
        for (int r = 0; r < 4; ++r) {
            const float mn = fmaxf(m_i[r], mx[r]);
            cor[r] = exp2f(m_i[r] - mn);
            m_i[r] = mn;
            lp[r] *= cor[r];
        }
        #pragma unroll
        for (int kg = 0; kg < 4; ++kg)
            #pragma unroll
            for (int r = 0; r < 4; ++r) {
                const float pj = exp2f(s[kg][r] - m_i[r]);
                lp[r] += pj;
                Ps[wave][quad * 4 + r][kg * 16 + l15] = f2bf(pj);
            }
        #pragma unroll
        for (int r = 0; r < 4; ++r) { o0[r] *= cor[r]; o1[r] *= cor[r]; }
        __syncthreads();

        const bf16x8 pa0 = *(const bf16x8*)&Ps[wave][l15][quad * 8];
        const bf16x8 pa1 = *(const bf16x8*)&Ps[wave][l15][32 + quad * 8];
        const bf16x8 vb00 = *(const bf16x8*)&Vs[l15][quad * 8];
        const bf16x8 vb01 = *(const bf16x8*)&Vs[16 + l15][quad * 8];
        const bf16x8 vb10 = *(const bf16x8*)&Vs[l15][32 + quad * 8];
        const bf16x8 vb11 = *(const bf16x8*)&Vs[16 + l15][32 + quad * 8];
        o0 = MFMA(pa0, vb00, o0);
        o0 = MFMA(pa1, vb10, o0);
        o1 = MFMA(pa0, vb01, o1);
        o1 = MFMA(pa1, vb11, o1);
    }

    #pragma unroll
    for (int mk = 1; mk < 16; mk <<= 1)
        #pragma unroll
        for (int r = 0; r < 4; ++r) lp[r] += __shfl_xor(lp[r], mk);

    const long base = (long)bh * KS + split;
    #pragma unroll
    for (int r = 0; r < 4; ++r) {
        const int pq = q0 + quad * 4 + r;
        if (pq < Nq) {
            if (l15 == 0) { pm[base * Nq + pq] = m_i[r]; pl[base * Nq + pq] = lp[r]; }
            pacc[(base * 32 + l15) * Nq + pq]      = o0[r];
            pacc[(base * 32 + 16 + l15) * Nq + pq] = o1[r];
        }
    }
}

// ---------------------------------------------------------------- fused epilogue: combine + Wm + Wc1(BN,ReLU) + Wc2 + resid
// grid: x = pos-tile(32), y = b. LDS chain in [pos][ch] bf16 tiles.
__global__ __launch_bounds__(256) void epi_kernel(
    const float* __restrict__ pm, const float* __restrict__ pl, const float* __restrict__ pacc, int KS,
    const float* __restrict__ x1,
    const u16* __restrict__ Wm, const float* __restrict__ bm,
    const u16* __restrict__ Wc1, const float* __restrict__ bc1,
    const float* __restrict__ bns, const float* __restrict__ bnsh,
    const u16* __restrict__ Wc2, const float* __restrict__ bc2,
    float* __restrict__ outF, float* __restrict__ outR, int Nq)
{
    __shared__ u16 Xa[32][136];   // add (m-conv input), [pos][128ch]
    __shared__ u16 Xc[32][264];   // [x1 ; m], [pos][256ch]
    __shared__ u16 Xh[32][264];   // h, [pos][256ch]
    const int tid = threadIdx.x;
    const int wid = tid >> 6, lane = tid & 63;
    const int l15 = lane & 15, quad = lane >> 4;
    const int b = blockIdx.y;
    const int p0 = blockIdx.x * 32;

    // ---- phase 1: combine splits -> Xa ; stage x1 -> Xc[:,0:128]
    {
        const int pos = tid & 31, sub = tid >> 5;       // 8 subs x 16 ch
        const int pp = (p0 + pos < Nq) ? p0 + pos : Nq - 1;
        const int h = sub >> 1, d0 = (sub & 1) * 16 + 0; // ch = (h*32) + (sub&1)*16 + i
        const int bh = b * 4 + h;
        float mg = -INFINITY;
        for (int s = 0; s < KS; ++s) mg = fmaxf(mg, pm[((long)bh * KS + s) * Nq + pp]);
        float lg = 0.f, acc[16];
        #pragma unroll
        for (int i = 0; i < 16; ++i) acc[i] = 0.f;
        for (int s = 0; s < KS; ++s) {
            const long base = (long)bh * KS + s;
            const float w = exp2f(pm[base * Nq + pp] - mg);
            lg += pl[base * Nq + pp] * w;
            #pragma unroll
            for (int i = 0; i < 16; ++i)
                acc[i] += pacc[(base * 32 + d0 + i) * Nq + pp] * w;
        }
        const float inv = 1.f / lg;
        bf16x8 v0, v1;
        #pragma unroll
        for (int i = 0; i < 8; ++i) { v0[i] = (short)f2bf(acc[i] * inv); v1[i] = (short)f2bf(acc[8 + i] * inv); }
        const int c0 = h * 32 + (sub & 1) * 16;
        *(bf16x8*)&Xa[pos][c0] = v0;
        *(bf16x8*)&Xa[pos][c0 + 8] = v1;
        // x1 -> Xc rows 0..127 (different thread map: pos=tid&31, cg=tid>>5 reuse sub)
        bf16x8 y0, y1;
        #pragma unroll
        for (int j = 0; j < 8; ++j) {
            y0[j] = (short)f2bf(x1[((long)b * 128 + sub * 16 + j) * Nq + pp]);
            y1[j] = (short)f2bf(x1[((long)b * 128 + sub * 16 + 8 + j) * Nq + pp]);
        }
        *(bf16x8*)&Xc[pos][sub * 16] = y0;
        *(bf16x8*)&Xc[pos][sub * 16 + 8] = y1;
    }
    __syncthreads();

    // ---- phase 2: m = Wm*add + bm -> Xc[:,128:256]
    {
        f32x4 am[2][2] = {};
        for (int k0 = 0; k0 < 128; k0 += 32) {
            #pragma unroll
            for (int og = 0; og < 2; ++og) {
                const bf16x8 af = *(const bf16x8*)(Wm + (long)(wid * 32 + og * 16 + l15) * 128 + k0 + quad * 8);
                #pragma unroll
                for (int pg = 0; pg < 2; ++pg) {
                    const bf16x8 bfr = *(const bf16x8*)&Xa[pg * 16 + l15][k0 + quad * 8];
                    am[og][pg] = MFMA(af, bfr, am[og][pg]);
                }
            }
        }
        #pragma unroll
        for (int og = 0; og < 2; ++og)
            #pragma unroll
            for (int pg = 0; pg < 2; ++pg)
                #pragma unroll
                for (int r = 0; r < 4; ++r) {
                    const int o = wid * 32 + og * 16 + quad * 4 + r;
                    Xc[pg * 16 + l15][128 + o] = f2bf(am[og][pg][r] + bm[o]);
                }
    }
    __syncthreads();

    // ---- phase 3: h = relu(bns*(Wc1*[x1;m]+bc1)+bnsh) -> Xh
    {
        f32x4 a1[4][2] = {};
        for (int k0 = 0; k0 < 256; k0 += 32) {
            #pragma unroll
            for (int og = 0; og < 4; ++og) {
                const bf16x8 af = *(const bf16x8*)(Wc1 + (long)(wid * 64 + og * 16 + l15) * 256 + k0 + quad * 8);
                #pragma unroll
                for (int pg = 0; pg < 2; ++pg) {
                    const bf16x8 bfr = *(const bf16x8*)&Xc[pg * 16 + l15][k0 + quad * 8];
                    a1[og][pg] = MFMA(af, bfr, a1[og][pg]);
                }
            }
        }
        #pragma unroll
        for (int og = 0; og < 4; ++og)
            #pragma unroll
            for (int pg = 0; pg < 2; ++pg)
                #pragma unroll
                for (int r = 0; r < 4; ++r) {
                    const int o = wid * 64 + og * 16 + quad * 4 + r;
                    const float hv = fmaxf((a1[og][pg][r] + bc1[o]) * bns[o] + bnsh[o], 0.f);
                    Xh[pg * 16 + l15][o] = f2bf(hv);
                }
    }
    __syncthreads();

    // ---- phase 4: y = Wc2*h + bc2 (+x1 resid) -> outF (+outR raw)
    {
        f32x4 a2[2][2] = {};
        for (int k0 = 0; k0 < 256; k0 += 32) {
            #pragma unroll
            for (int og = 0; og < 2; ++og) {
                const bf16x8 af = *(const bf16x8*)(Wc2 + (long)(wid * 32 + og * 16 + l15) * 256 + k0 + quad * 8);
                #pragma unroll
                for (int pg = 0; pg < 2; ++pg) {
                    const bf16x8 bfr = *(const bf16x8*)&Xh[pg * 16 + l15][k0 + quad * 8];
                    a2[og][pg] = MFMA(af, bfr, a2[og][pg]);
                }
            }
        }
        #pragma unroll
        for (int og = 0; og < 2; ++og)
            #pragma unroll
            for (int pg = 0; pg < 2; ++pg)
                #pragma unroll
                for (int r = 0; r < 4; ++r) {
                    const int o = wid * 32 + og * 16 + quad * 4 + r;
                    const int p = p0 + pg * 16 + l15;
                    if (p < Nq) {
                        const long idx = ((long)b * 128 + o) * Nq + p;
                        const float v = a2[og][pg][r] + bc2[o];
                        outF[idx] = v + x1[idx];
                        if (outR) outR[idx] = v;
                    }
                }
    }
}

// ---------------------------------------------------------------- tail1: conv 128->64 (MFMA) + atomic stats
__global__ __launch_bounds__(256) void tail1_kernel(
    const float* __restrict__ X, const u16* __restrict__ W, const float* __restrict__ bias,
    float* __restrict__ Y, float* __restrict__ ps, float* __restrict__ pq, int P)
{
    __shared__ u16 Xt[64][40];
    const int tid = threadIdx.x;
    const int wid = tid >> 6, lane = tid & 63;
    const int l15 = lane & 15, quad = lane >> 4;
    const int b = blockIdx.y;
    const int p0 = blockIdx.x * 64;
    const int sp = tid & 63, cg = tid >> 6;
    f32x4 acc[4] = {};
    for (int k0 = 0; k0 < 128; k0 += 32) {
        bf16x8 st;
        {
            const int pp = (p0 + sp < P) ? p0 + sp : P - 1;
            #pragma unroll
            for (int j = 0; j < 8; ++j)
                st[j] = (short)f2bf(X[((long)b * 128 + k0 + cg * 8 + j) * P + pp]);
        }
        __syncthreads();
        *(bf16x8*)&Xt[sp][cg * 8] = st;
        __syncthreads();
        const bf16x8 af = *(const bf16x8*)(W + (long)(wid * 16 + l15) * 128 + k0 + quad * 8);
        #pragma unroll
        for (int pg = 0; pg < 4; ++pg) {
            const bf16x8 bfr = *(const bf16x8*)&Xt[pg * 16 + l15][quad * 8];
            acc[pg] = MFMA(af, bfr, acc[pg]);
        }
    }
    float sums[4] = {}, sq[4] = {};
    #pragma unroll
    for (int pg = 0; pg < 4; ++pg)
        #pragma unroll
        for (int r = 0; r < 4; ++r) {
            const int o = wid * 16 + quad * 4 + r;
            const int p = p0 + pg * 16 + l15;
            if (p < P) {
                const float v = acc[pg][r] + bias[o];
                Y[((long)b * 64 + o) * P + p] = v;
                sums[r] += v; sq[r] += v * v;
            }
        }
    #pragma unroll
    for (int mk = 1; mk < 16; mk <<= 1)
        #pragma unroll
        for (int r = 0; r < 4; ++r) { sums[r] += __shfl_xor(sums[r], mk); sq[r] += __shfl_xor(sq[r], mk); }
    if (l15 == 0)
        #pragma unroll
        for (int r = 0; r < 4; ++r) {
            const int o = wid * 16 + quad * 4 + r;
            atomicAdd(&ps[b * 64 + o], sums[r]);
            atomicAdd(&pq[b * 64 + o], sq[r]);
        }
}

// ---------------------------------------------------------------- tail mid: norm(prev) -> conv -> stats
template<int CI, int CO>
__global__ __launch_bounds__(256) void tail_mid(
    const float* __restrict__ xraw, const float* __restrict__ ps, const float* __restrict__ pq,
    const float* __restrict__ sc, const float* __restrict__ sh,
    const float* __restrict__ W, const float* __restrict__ bias,
    float* __restrict__ ps2, float* __restrict__ pq2, float* __restrict__ yraw, int P)
{
    __shared__ float k1s[CI], k2s[CI], Wl[CO * CI];
    const int tid = threadIdx.x;
    const int b = blockIdx.y;
    for (int i = tid; i < CO * CI; i += 256) Wl[i] = W[i];
    if (tid < CI) {
        const float S = ps[b * CI + tid], Q2 = pq[b * CI + tid];
        const float mu = S / P;
        const float var = Q2 / P - mu * mu;
        const float rs = rsqrtf(var + 1e-3f);
        k1s[tid] = rs * sc[tid];
        k2s[tid] = sh[tid] - mu * rs * sc[tid];
    }
    __syncthreads();
    const int p = blockIdx.x * 256 + tid;
    const bool valid = p < P;
    const int pp = valid ? p : P - 1;
    float acc[CO];
    #pragma unroll
    for (int o = 0; o < CO; ++o) acc[o] = bias[o];
    for (int c = 0; c < CI; ++c) {
        const float xn = fmaxf(xraw[((long)b * CI + c) * P + pp] * k1s[c] + k2s[c], 0.f);
        #pragma unroll
        for (int o = 0; o < CO; ++o) acc[o] += Wl[o * CI + c] * xn;
    }
    float sums[CO], sq[CO];
    #pragma unroll
    for (int o = 0; o < CO; ++o) {
        const float v = acc[o];
        if (valid) yraw[((long)b * CO + o) * P + p] = v;
        sums[o] = valid ? v : 0.f;
        sq[o] = valid ? v * v : 0.f;
    }
    #pragma unroll
    for (int mk = 1; mk < 64; mk <<= 1)
        #pragma unroll
        for (int o = 0; o < CO; ++o) { sums[o] += __shfl_xor(sums[o], mk); sq[o] += __shfl_xor(sq[o], mk); }
    if ((tid & 63) == 0)
        #pragma unroll
        for (int o = 0; o < CO; ++o) {
            atomicAdd(&ps2[b * CO + o], sums[o]);
            atomicAdd(&pq2[b * CO + o], sq[o]);
        }
}

// ---------------------------------------------------------------- tail4: norm3 -> conv 4->1 -> logits
__global__ __launch_bounds__(256) void tail4_kernel(
    const float* __restrict__ xraw, const float* __restrict__ ps, const float* __restrict__ pq,
    const float* __restrict__ sc, const float* __restrict__ sh,
    const float* __restrict__ W4, const float* __restrict__ b4,
    float* __restrict__ out, int P)
{
    const int tid = threadIdx.x;
    const int b = blockIdx.y;
    const int p = blockIdx.x * 256 + tid;
    if (p >= P) return;
    float acc = b4[0];
    #pragma unroll
    for (int c = 0; c < 4; ++c) {
        const float S = ps[b * 4 + c], Q2 = pq[b * 4 + c];
        const float mu = S / P;
        const float var = Q2 / P - mu * mu;
        const float rs = rsqrtf(var + 1e-3f);
        const float k1 = rs * sc[c], k2 = sh[c] - mu * rs * sc[c];
        const float xn = fmaxf(xraw[((long)b * 4 + c) * P + p] * k1 + k2, 0.f);
        acc += W4[c] * xn;
    }
    out[(long)b * P + p] = acc;
}

// ================================================================ host
extern "C" void kernel_launch(void* const* d_in, const int* in_sizes, int n_in,
                              void* d_out, int out_size, void* d_ws, size_t ws_size,
                              hipStream_t stream)
{
    const float* dX   = (const float*)d_in[1];
    const float* fpX  = (const float*)d_in[2];
    const float* lgin = (const float*)d_in[3];
    const float* Wq = (const float*)d_in[4];  const float* bq = (const float*)d_in[5];
    const float* Wk = (const float*)d_in[6];  const float* bk = (const float*)d_in[7];
    const float* Wv = (const float*)d_in[8];  const float* bv = (const float*)d_in[9];
    const float* Wm = (const float*)d_in[10]; const float* bm = (const float*)d_in[11];
    const float* Wc1= (const float*)d_in[12]; const float* bc1= (const float*)d_in[13];
    const float* bns= (const float*)d_in[14]; const float* bnsh=(const float*)d_in[15];
    const float* Wc2= (const float*)d_in[16]; const float* bc2= (const float*)d_in[17];
    const float* iW1= (const float*)d_in[18]; const float* ib1= (const float*)d_in[19];
    const float* s1 = (const float*)d_in[20]; const float* h1 = (const float*)d_in[21];
    const float* iW2= (const float*)d_in[22]; const float* ib2= (const float*)d_in[23];
    const float* s2 = (const float*)d_in[24]; const float* h2 = (const float*)d_in[25];
    const float* iW3= (const float*)d_in[26]; const float* ib3= (const float*)d_in[27];
    const float* s3 = (const float*)d_in[28]; const float* h3 = (const float*)d_in[29];
    const float* iW4= (const float*)d_in[30]; const float* ib4= (const float*)d_in[31];

    float* out_d      = (float*)d_out;                 // [2,128,6000]
    float* out_logits = out_d + (long)B_ * C_ * N_;    // [2,6000]

    float* f = (float*)d_ws;
    long off = 0;
    auto alloc = [&](long n) { float* p = f + off; off += n; return p; };
    float* featA = alloc(384000);
    float* featB = alloc(384000);
    float* qb    = alloc(1536000);
    float* kb    = alloc(1536000);
    float* vb    = alloc(1536000);
    float* xb    = alloc(1536000);
    float* x1raw = alloc(768000);
    float* x2raw = alloc(192000);
    float* x3raw = alloc(48000);
    float* pmb   = alloc(64000);
    float* plb   = alloc(64000);
    float* pacc  = alloc(1600000);
    float* zst   = alloc(512);       // stats accumulators (zeroed by prep)
    float* wreg  = alloc(250000);    // 500K bf16 weights
    (void)ws_size; (void)in_sizes; (void)n_in; (void)out_size;

    float* ps1 = zst;        float* pq1 = zst + 128;
    float* ps2 = zst + 256;  float* pq2 = zst + 288;
    float* ps3 = zst + 320;  float* pq3 = zst + 328;

    u16* wq_h  = (u16*)wreg;
    u16* wk_h  = wq_h + 49152;
    u16* wv_h  = wk_h + 49152;
    u16* wm_h  = wv_h + 49152;
    u16* wc1_h = wm_h + 49152;
    u16* wc2_h = wc1_h + 196608;
    u16* w1_h  = wc2_h + 98304;

    prep_kernel<<<dim3(768), 256, 0, stream>>>(Wq, Wk, Wv, Wm, Wc1, Wc2, iW1,
                                               wq_h, wk_h, wv_h, wm_h, wc1_h, wc2_h, w1_h, zst);

    auto layer = [&](const float* x1, const float* x2, int Nq, int Nk,
                     const float* maskl, int li, int KS, int chunkLen,
                     float* outF, float* outR) {
        qkv_kernel<<<dim3((max(Nq, Nk) + 63) / 64, 6, B_), 256, 0, stream>>>(
            x1, x2, Nq, Nk,
            wq_h + (long)li * 16384, wk_h + (long)li * 16384, wv_h + (long)li * 16384,
            bq + li * 128, bk + li * 128, bv + li * 128, qb, kb, vb);
        attn_partial<<<dim3((Nq + 63) / 64, B_ * H_, KS), 256, 0, stream>>>(
            qb, kb, vb, maskl, pmb, plb, pacc, Nq, Nk, KS, chunkLen);
        epi_kernel<<<dim3((Nq + 31) / 32, B_), 256, 0, stream>>>(
            pmb, plb, pacc, KS, x1,
            wm_h + (long)li * 16384, bm + li * 128,
            wc1_h + (long)li * 65536, bc1 + li * 256, bns + li * 256, bnsh + li * 256,
            wc2_h + (long)li * 32768, bc2 + li * 128,
            outF, outR, Nq);
    };

    layer(fpX,   dX,    M_, N_, lgin,    0, 4, 1536, featA, nullptr);
    layer(featA, featA, M_, M_, nullptr, 1, 2, 768,  featB, nullptr);
    layer(dX,    featB, N_, M_, nullptr, 2, 1, 1536, out_d, xb);

    tail1_kernel<<<dim3((N_ + 63) / 64, B_), 256, 0, stream>>>(xb, w1_h, ib1, x1raw, ps1, pq1, N_);
    tail_mid<64, 16><<<dim3((N_ + 255) / 256, B_), 256, 0, stream>>>(
        x1raw, ps1, pq1, s1, h1, iW2, ib2, ps2, pq2, x2raw, N_);
    tail_mid<16, 4><<<dim3((N_ + 255) / 256, B_), 256, 0, stream>>>(
        x2raw, ps2, pq2, s2, h2, iW3, ib3, ps3, pq3, x3raw, N_);
    tail4_kernel<<<dim3((N_ + 255) / 256, B_), 256, 0, stream>>>(
        x3raw, ps3, pq3, s3, h3, iW4, ib4, out_logits, N_);
}

// Round 6
// 456.079 us; speedup vs baseline: 2.5927x; 1.0293x over previous
//
#include <hip/hip_runtime.h>
#include <math.h>

#define B_  2
#define C_  128
#define N_  6000
#define M_  1500
#define H_  4
#define DH_ 32

typedef __attribute__((ext_vector_type(8))) short bf16x8;   // 8 bf16 = 4 VGPRs
typedef __attribute__((ext_vector_type(4))) float f32x4;
typedef unsigned short u16;

static __device__ __forceinline__ u16 f2bf(float x) {
    unsigned u = __float_as_uint(x);
    return (u16)((u + 0x7fffu + ((u >> 16) & 1u)) >> 16);   // RNE
}
#define MFMA(a,b,c) __builtin_amdgcn_mfma_f32_16x16x32_bf16((a),(b),(c),0,0,0)
// exp2-domain softmax: scores scaled by (1/sqrt(32))*log2(e)
#define INVS2 (0.17677669529663687f * 1.4426950408889634f)

// ---------------------------------------------------------------- prep: weights->bf16, zero stats
__global__ __launch_bounds__(256) void prep_kernel(
    const float* __restrict__ Wq, const float* __restrict__ Wk, const float* __restrict__ Wv,
    const float* __restrict__ Wm, const float* __restrict__ Wc1, const float* __restrict__ Wc2,
    const float* __restrict__ iW1,
    u16* __restrict__ wq, u16* __restrict__ wk, u16* __restrict__ wv, u16* __restrict__ wm,
    u16* __restrict__ wc1, u16* __restrict__ wc2, u16* __restrict__ w1,
    float* __restrict__ zstats)
{
    long i = (long)blockIdx.x * 256 + threadIdx.x;
    if (i < 512)    zstats[i] = 0.f;
    if (i < 49152)  { wq[i] = f2bf(Wq[i]); wk[i] = f2bf(Wk[i]);
                      wv[i] = f2bf(Wv[i]); wm[i] = f2bf(Wm[i]); }
    if (i < 196608) wc1[i] = f2bf(Wc1[i]);
    if (i < 98304)  wc2[i] = f2bf(Wc2[i]);
    if (i < 8192)   w1[i]  = f2bf(iW1[i]);
}

// ---------------------------------------------------------------- fused q/k/v conv (MFMA, CIN=128)
// grid: x = pos-tile(64), y = job*2+otile (job 0:q 1:k 2:v), z = b
__global__ __launch_bounds__(256) void qkv_kernel(
    const float* __restrict__ x1, const float* __restrict__ x2, int Pq, int Pk,
    const u16* __restrict__ wq, const u16* __restrict__ wk, const u16* __restrict__ wv,
    const float* __restrict__ bq, const float* __restrict__ bk, const float* __restrict__ bv,
    float* __restrict__ qb, float* __restrict__ kb, float* __restrict__ vb)
{
    __shared__ u16 Xt[64][40];      // [pos][cin-chunk], row 80B
    const int tid = threadIdx.x;
    const int wid = tid >> 6, lane = tid & 63;
    const int l15 = lane & 15, quad = lane >> 4;
    const int job = blockIdx.y >> 1, ot = blockIdx.y & 1;
    const int b = blockIdx.z;
    const int p0 = blockIdx.x * 64;
    const float* X; const u16* W; const float* bias; float* Y; int P;
    if (job == 0)      { X = x1; W = wq; bias = bq; Y = qb; P = Pq; }
    else if (job == 1) { X = x2; W = wk; bias = bk; Y = kb; P = Pk; }
    else               { X = x2; W = wv; bias = bv; Y = vb; P = Pk; }
    if (p0 >= P) return;
    const long xoff = (long)b * C_ * P;
    const int sp = tid & 63, cg = tid >> 6;
    f32x4 acc[4] = {};

    for (int k0 = 0; k0 < 128; k0 += 32) {
        bf16x8 st;
        {
            const int pp = (p0 + sp < P) ? p0 + sp : P - 1;
            #pragma unroll
            for (int j = 0; j < 8; ++j)
                st[j] = (short)f2bf(X[xoff + (long)(k0 + cg * 8 + j) * P + pp]);
        }
        __syncthreads();
        *(bf16x8*)&Xt[sp][cg * 8] = st;
        __syncthreads();
        const bf16x8 af = *(const bf16x8*)(W + (long)(ot * 64 + wid * 16 + l15) * 128 + k0 + quad * 8);
        #pragma unroll
        for (int pg = 0; pg < 4; ++pg) {
            const bf16x8 bfr = *(const bf16x8*)&Xt[pg * 16 + l15][quad * 8];
            acc[pg] = MFMA(af, bfr, acc[pg]);
        }
    }
    #pragma unroll
    for (int pg = 0; pg < 4; ++pg)
        #pragma unroll
        for (int r = 0; r < 4; ++r) {
            const int o = ot * 64 + wid * 16 + quad * 4 + r;
            const int p = p0 + pg * 16 + l15;
            if (p < P) Y[((long)b * 128 + o) * P + p] = acc[pg][r] + bias[o];
        }
}

// ---------------------------------------------------------------- flash attention (MFMA, partials)
// 1D grid, id = (qb*KS+split)*8 + bh  ->  id%8==bh pins each head's K/V chunk to one XCD.
// Register-prefetched K/V/mask staging double-buffers global latency against compute.
__global__ __launch_bounds__(256) void attn_partial(
    const float* __restrict__ Q, const float* __restrict__ K, const float* __restrict__ V,
    const float* __restrict__ lgin,
    float* __restrict__ pm, float* __restrict__ pl, float* __restrict__ pacc,
    int Nq, int Nk, int KS, int chunkLen)   // chunkLen multiple of 64
{
    __shared__ u16 Ks[64][40];     // [key][dh]
    __shared__ u16 Vs[32][72];     // [dh][key]
    __shared__ u16 Ps[4][16][72];  // per-wave P round-trip
    __shared__ float biasS[64];

    const int tid  = threadIdx.x;
    const int wave = tid >> 6, lane = tid & 63;
    const int l15  = lane & 15, quad = lane >> 4;
    const int bid  = blockIdx.x;
    const int bh   = bid & 7, rest = bid >> 3;
    const int split = rest % KS, qblk = rest / KS;
    const int b = bh >> 2, h = bh & 3;
    const int q0 = qblk * 64 + wave * 16;

    const long qoff = ((long)b * C_ + h * DH_) * Nq;
    const long koff = ((long)b * C_ + h * DH_) * Nk;

    bf16x8 qa;
    {
        int qq = q0 + l15; if (qq >= Nq) qq = Nq - 1;
        #pragma unroll
        for (int j = 0; j < 8; ++j)
            qa[j] = (short)f2bf(Q[qoff + (long)(quad * 8 + j) * Nq + qq]);
    }

    float m_i[4] = {-INFINITY, -INFINITY, -INFINITY, -INFINITY};
    float lp[4]  = {0.f, 0.f, 0.f, 0.f};
    f32x4 o0 = {0.f, 0.f, 0.f, 0.f}, o1 = {0.f, 0.f, 0.f, 0.f};

    const int kbeg = split * chunkLen;
    const int kend = min(Nk, kbeg + chunkLen);
    const int kkey = tid & 63, dg = tid >> 6;   // K staging: per-key b128 along dh
    const int key2 = tid & 31, dv = tid >> 5;   // V staging: key-pair u32 writes

    float krf[8], vxf[4], vyf[4], lgr = 1.f;
    auto stage = [&](int m0) {                  // global -> regs (latency overlapped)
        int mmc = m0 + kkey; if (mmc >= Nk) mmc = Nk - 1;
        #pragma unroll
        for (int j = 0; j < 8; ++j)
            krf[j] = K[koff + (long)(dg * 8 + j) * Nk + mmc];
        const int kA = m0 + 2 * key2;
        if (kA + 1 < Nk) {
            #pragma unroll
            for (int i = 0; i < 4; ++i) {
                float2 t = *(const float2*)&V[koff + (long)(dv * 4 + i) * Nk + kA];
                vxf[i] = t.x; vyf[i] = t.y;
            }
        } else {
            const int a0 = kA < Nk ? kA : Nk - 1, a1 = kA + 1 < Nk ? kA + 1 : Nk - 1;
            #pragma unroll
            for (int i = 0; i < 4; ++i) {
                const float* vp = &V[koff + (long)(dv * 4 + i) * Nk];
                vxf[i] = vp[a0]; vyf[i] = vp[a1];
            }
        }
        if (lgin && tid < 64) {
            const int mm = m0 + tid;
            lgr = (mm < Nk) ? lgin[(long)b * Nk + mm] : 1.f;
        }
    };

    stage(kbeg);
    for (int m0 = kbeg; m0 < kend; m0 += 64) {
        __syncthreads();                        // prior compute done with Ks/Vs
        {   // commit regs -> LDS (bf16 conversion here)
            bf16x8 kr;
            #pragma unroll
            for (int j = 0; j < 8; ++j) kr[j] = (short)f2bf(krf[j]);
            *(bf16x8*)&Ks[kkey][dg * 8] = kr;
            #pragma unroll
            for (int i = 0; i < 4; ++i)
                *(unsigned*)&Vs[dv * 4 + i][2 * key2] =
                    (unsigned)f2bf(vxf[i]) | ((unsigned)f2bf(vyf[i]) << 16);
            if (tid < 64) {
                const int mm = m0 + tid;
                float bv = -3e29f;                                  // out-of-range
                if (mm < kend) bv = (lgin && !(lgr > 0.f)) ? (-1e6f * INVS2) : 0.f;
                biasS[tid] = bv;
            }
        }
        __syncthreads();
        if (m0 + 64 < kend) stage(m0 + 64);     // prefetch next tile

        f32x4 sacc[4];
        #pragma unroll
        for (int kg = 0; kg < 4; ++kg) {
            sacc[kg] = (f32x4){0.f, 0.f, 0.f, 0.f};
            const bf16x8 kb_ = *(const bf16x8*)&Ks[kg * 16 + l15][quad * 8];
            sacc[kg] = MFMA(qa, kb_, sacc[kg]);
        }

        float s[4][4], mx[4];
        #pragma unroll
        for (int kg = 0; kg < 4; ++kg) {
            const float bv = biasS[kg * 16 + l15];
            #pragma unroll
            for (int r = 0; r < 4; ++r) s[kg][r] = fmaf(sacc[kg][r], INVS2, bv);
        }
        #pragma unroll
        for (int r = 0; r < 4; ++r)
            mx[r] = fmaxf(fmaxf(s[0][r], s[1][r]), fmaxf(s[2][r], s[3][r]));
        #pragma unroll
        for (int mk = 1; mk < 16; mk <<= 1)
            #pragma unroll
            for (int r = 0; r < 4; ++r)
                mx[r] = fmaxf(mx[r], __shfl_xor(mx[r], mk));
        float cor[4];
        #pragma unroll
        for (int r = 0; r < 4; ++r) {
            const float mn = fmaxf(m_i[r], mx[r]);
            cor[r] = exp2f(m_i[r] - mn);
            m_i[r] = mn;
            lp[r] *= cor[r];
        }
        #pragma unroll
        for (int kg = 0; kg < 4; ++kg)
            #pragma unroll
            for (int r = 0; r < 4; ++r) {
                const float pj = exp2f(s[kg][r] - m_i[r]);
                lp[r] += pj;
                Ps[wave][quad * 4 + r][kg * 16 + l15] = f2bf(pj);
            }
        #pragma unroll
        for (int r = 0; r < 4; ++r) { o0[r] *= cor[r]; o1[r] *= cor[r]; }
        __syncthreads();

        const bf16x8 pa0 = *(const bf16x8*)&Ps[wave][l15][quad * 8];
        const bf16x8 pa1 = *(const bf16x8*)&Ps[wave][l15][32 + quad * 8];
        const bf16x8 vb00 = *(const bf16x8*)&Vs[l15][quad * 8];
        const bf16x8 vb01 = *(const bf16x8*)&Vs[16 + l15][quad * 8];
        const bf16x8 vb10 = *(const bf16x8*)&Vs[l15][32 + quad * 8];
        const bf16x8 vb11 = *(const bf16x8*)&Vs[16 + l15][32 + quad * 8];
        o0 = MFMA(pa0, vb00, o0);
        o0 = MFMA(pa1, vb10, o0);
        o1 = MFMA(pa0, vb01, o1);
        o1 = MFMA(pa1, vb11, o1);
    }

    #pragma unroll
    for (int mk = 1; mk < 16; mk <<= 1)
        #pragma unroll
        for (int r = 0; r < 4; ++r) lp[r] += __shfl_xor(lp[r], mk);

    const long base = (long)bh * KS + split;
    #pragma unroll
    for (int r = 0; r < 4; ++r) {
        const int pq = q0 + quad * 4 + r;
        if (pq < Nq) {
            if (l15 == 0) { pm[base * Nq + pq] = m_i[r]; pl[base * Nq + pq] = lp[r]; }
            pacc[(base * 32 + l15) * Nq + pq]      = o0[r];
            pacc[(base * 32 + 16 + l15) * Nq + pq] = o1[r];
        }
    }
}

// ---------------------------------------------------------------- fused epilogue: combine + Wm + Wc1(BN,ReLU) + Wc2 + resid
__global__ __launch_bounds__(256) void epi_kernel(
    const float* __restrict__ pm, const float* __restrict__ pl, const float* __restrict__ pacc, int KS,
    const float* __restrict__ x1,
    const u16* __restrict__ Wm, const float* __restrict__ bm,
    const u16* __restrict__ Wc1, const float* __restrict__ bc1,
    const float* __restrict__ bns, const float* __restrict__ bnsh,
    const u16* __restrict__ Wc2, const float* __restrict__ bc2,
    float* __restrict__ outF, float* __restrict__ outR, int Nq)
{
    __shared__ u16 Xa[32][136];   // add (m-conv input), [pos][128ch]
    __shared__ u16 Xc[32][264];   // [x1 ; m], [pos][256ch]
    __shared__ u16 Xh[32][264];   // h, [pos][256ch]
    const int tid = threadIdx.x;
    const int wid = tid >> 6, lane = tid & 63;
    const int l15 = lane & 15, quad = lane >> 4;
    const int b = blockIdx.y;
    const int p0 = blockIdx.x * 32;

    // ---- phase 1: combine splits -> Xa ; stage x1 -> Xc[:,0:128]
    {
        const int pos = tid & 31, sub = tid >> 5;
        const int pp = (p0 + pos < Nq) ? p0 + pos : Nq - 1;
        const int h = sub >> 1, d0 = (sub & 1) * 16;
        const int bh = b * 4 + h;
        float mg = -INFINITY;
        for (int s = 0; s < KS; ++s) mg = fmaxf(mg, pm[((long)bh * KS + s) * Nq + pp]);
        float lg = 0.f, acc[16];
        #pragma unroll
        for (int i = 0; i < 16; ++i) acc[i] = 0.f;
        for (int s = 0; s < KS; ++s) {
            const long base = (long)bh * KS + s;
            const float w = exp2f(pm[base * Nq + pp] - mg);
            lg += pl[base * Nq + pp] * w;
            #pragma unroll
            for (int i = 0; i < 16; ++i)
                acc[i] += pacc[(base * 32 + d0 + i) * Nq + pp] * w;
        }
        const float inv = 1.f / lg;
        bf16x8 v0, v1;
        #pragma unroll
        for (int i = 0; i < 8; ++i) { v0[i] = (short)f2bf(acc[i] * inv); v1[i] = (short)f2bf(acc[8 + i] * inv); }
        const int c0 = h * 32 + (sub & 1) * 16;
        *(bf16x8*)&Xa[pos][c0] = v0;
        *(bf16x8*)&Xa[pos][c0 + 8] = v1;
        bf16x8 y0, y1;
        #pragma unroll
        for (int j = 0; j < 8; ++j) {
            y0[j] = (short)f2bf(x1[((long)b * 128 + sub * 16 + j) * Nq + pp]);
            y1[j] = (short)f2bf(x1[((long)b * 128 + sub * 16 + 8 + j) * Nq + pp]);
        }
        *(bf16x8*)&Xc[pos][sub * 16] = y0;
        *(bf16x8*)&Xc[pos][sub * 16 + 8] = y1;
    }
    __syncthreads();

    // ---- phase 2: m = Wm*add + bm -> Xc[:,128:256]
    {
        f32x4 am[2][2] = {};
        for (int k0 = 0; k0 < 128; k0 += 32) {
            #pragma unroll
            for (int og = 0; og < 2; ++og) {
                const bf16x8 af = *(const bf16x8*)(Wm + (long)(wid * 32 + og * 16 + l15) * 128 + k0 + quad * 8);
                #pragma unroll
                for (int pg = 0; pg < 2; ++pg) {
                    const bf16x8 bfr = *(const bf16x8*)&Xa[pg * 16 + l15][k0 + quad * 8];
                    am[og][pg] = MFMA(af, bfr, am[og][pg]);
                }
            }
        }
        #pragma unroll
        for (int og = 0; og < 2; ++og)
            #pragma unroll
            for (int pg = 0; pg < 2; ++pg)
                #pragma unroll
                for (int r = 0; r < 4; ++r) {
                    const int o = wid * 32 + og * 16 + quad * 4 + r;
                    Xc[pg * 16 + l15][128 + o] = f2bf(am[og][pg][r] + bm[o]);
                }
    }
    __syncthreads();

    // ---- phase 3: h = relu(bns*(Wc1*[x1;m]+bc1)+bnsh) -> Xh
    {
        f32x4 a1[4][2] = {};
        for (int k0 = 0; k0 < 256; k0 += 32) {
            #pragma unroll
            for (int og = 0; og < 4; ++og) {
                const bf16x8 af = *(const bf16x8*)(Wc1 + (long)(wid * 64 + og * 16 + l15) * 256 + k0 + quad * 8);
                #pragma unroll
                for (int pg = 0; pg < 2; ++pg) {
                    const bf16x8 bfr = *(const bf16x8*)&Xc[pg * 16 + l15][k0 + quad * 8];
                    a1[og][pg] = MFMA(af, bfr, a1[og][pg]);
                }
            }
        }
        #pragma unroll
        for (int og = 0; og < 4; ++og)
            #pragma unroll
            for (int pg = 0; pg < 2; ++pg)
                #pragma unroll
                for (int r = 0; r < 4; ++r) {
                    const int o = wid * 64 + og * 16 + quad * 4 + r;
                    const float hv = fmaxf((a1[og][pg][r] + bc1[o]) * bns[o] + bnsh[o], 0.f);
                    Xh[pg * 16 + l15][o] = f2bf(hv);
                }
    }
    __syncthreads();

    // ---- phase 4: y = Wc2*h + bc2 (+x1 resid) -> outF (+outR raw)
    {
        f32x4 a2[2][2] = {};
        for (int k0 = 0; k0 < 256; k0 += 32) {
            #pragma unroll
            for (int og = 0; og < 2; ++og) {
                const bf16x8 af = *(const bf16x8*)(Wc2 + (long)(wid * 32 + og * 16 + l15) * 256 + k0 + quad * 8);
                #pragma unroll
                for (int pg = 0; pg < 2; ++pg) {
                    const bf16x8 bfr = *(const bf16x8*)&Xh[pg * 16 + l15][k0 + quad * 8];
                    a2[og][pg] = MFMA(af, bfr, a2[og][pg]);
                }
            }
        }
        #pragma unroll
        for (int og = 0; og < 2; ++og)
            #pragma unroll
            for (int pg = 0; pg < 2; ++pg)
                #pragma unroll
                for (int r = 0; r < 4; ++r) {
                    const int o = wid * 32 + og * 16 + quad * 4 + r;
                    const int p = p0 + pg * 16 + l15;
                    if (p < Nq) {
                        const long idx = ((long)b * 128 + o) * Nq + p;
                        const float v = a2[og][pg][r] + bc2[o];
                        outF[idx] = v + x1[idx];
                        if (outR) outR[idx] = v;
                    }
                }
    }
}

// ---------------------------------------------------------------- tail1: conv 128->64 (MFMA) + atomic stats
__global__ __launch_bounds__(256) void tail1_kernel(
    const float* __restrict__ X, const u16* __restrict__ W, const float* __restrict__ bias,
    float* __restrict__ Y, float* __restrict__ ps, float* __restrict__ pq, int P)
{
    __shared__ u16 Xt[64][40];
    const int tid = threadIdx.x;
    const int wid = tid >> 6, lane = tid & 63;
    const int l15 = lane & 15, quad = lane >> 4;
    const int b = blockIdx.y;
    const int p0 = blockIdx.x * 64;
    const int sp = tid & 63, cg = tid >> 6;
    f32x4 acc[4] = {};
    for (int k0 = 0; k0 < 128; k0 += 32) {
        bf16x8 st;
        {
            const int pp = (p0 + sp < P) ? p0 + sp : P - 1;
            #pragma unroll
            for (int j = 0; j < 8; ++j)
                st[j] = (short)f2bf(X[((long)b * 128 + k0 + cg * 8 + j) * P + pp]);
        }
        __syncthreads();
        *(bf16x8*)&Xt[sp][cg * 8] = st;
        __syncthreads();
        const bf16x8 af = *(const bf16x8*)(W + (long)(wid * 16 + l15) * 128 + k0 + quad * 8);
        #pragma unroll
        for (int pg = 0; pg < 4; ++pg) {
            const bf16x8 bfr = *(const bf16x8*)&Xt[pg * 16 + l15][quad * 8];
            acc[pg] = MFMA(af, bfr, acc[pg]);
        }
    }
    float sums[4] = {}, sq[4] = {};
    #pragma unroll
    for (int pg = 0; pg < 4; ++pg)
        #pragma unroll
        for (int r = 0; r < 4; ++r) {
            const int o = wid * 16 + quad * 4 + r;
            const int p = p0 + pg * 16 + l15;
            if (p < P) {
                const float v = acc[pg][r] + bias[o];
                Y[((long)b * 64 + o) * P + p] = v;
                sums[r] += v; sq[r] += v * v;
            }
        }
    #pragma unroll
    for (int mk = 1; mk < 16; mk <<= 1)
        #pragma unroll
        for (int r = 0; r < 4; ++r) { sums[r] += __shfl_xor(sums[r], mk); sq[r] += __shfl_xor(sq[r], mk); }
    if (l15 == 0)
        #pragma unroll
        for (int r = 0; r < 4; ++r) {
            const int o = wid * 16 + quad * 4 + r;
            atomicAdd(&ps[b * 64 + o], sums[r]);
            atomicAdd(&pq[b * 64 + o], sq[r]);
        }
}

// ---------------------------------------------------------------- tail mid: norm(prev) -> conv -> stats
template<int CI, int CO>
__global__ __launch_bounds__(256) void tail_mid(
    const float* __restrict__ xraw, const float* __restrict__ ps, const float* __restrict__ pq,
    const float* __restrict__ sc, const float* __restrict__ sh,
    const float* __restrict__ W, const float* __restrict__ bias,
    float* __restrict__ ps2, float* __restrict__ pq2, float* __restrict__ yraw, int P)
{
    __shared__ float k1s[CI], k2s[CI], Wl[CO * CI];
    const int tid = threadIdx.x;
    const int b = blockIdx.y;
    for (int i = tid; i < CO * CI; i += 256) Wl[i] = W[i];
    if (tid < CI) {
        const float S = ps[b * CI + tid], Q2 = pq[b * CI + tid];
        const float mu = S / P;
        const float var = Q2 / P - mu * mu;
        const float rs = rsqrtf(var + 1e-3f);
        k1s[tid] = rs * sc[tid];
        k2s[tid] = sh[tid] - mu * rs * sc[tid];
    }
    __syncthreads();
    const int p = blockIdx.x * 256 + tid;
    const bool valid = p < P;
    const int pp = valid ? p : P - 1;
    float acc[CO];
    #pragma unroll
    for (int o = 0; o < CO; ++o) acc[o] = bias[o];
    for (int c = 0; c < CI; ++c) {
        const float xn = fmaxf(xraw[((long)b * CI + c) * P + pp] * k1s[c] + k2s[c], 0.f);
        #pragma unroll
        for (int o = 0; o < CO; ++o) acc[o] += Wl[o * CI + c] * xn;
    }
    float sums[CO], sq[CO];
    #pragma unroll
    for (int o = 0; o < CO; ++o) {
        const float v = acc[o];
        if (valid) yraw[((long)b * CO + o) * P + p] = v;
        sums[o] = valid ? v : 0.f;
        sq[o] = valid ? v * v : 0.f;
    }
    #pragma unroll
    for (int mk = 1; mk < 64; mk <<= 1)
        #pragma unroll
        for (int o = 0; o < CO; ++o) { sums[o] += __shfl_xor(sums[o], mk); sq[o] += __shfl_xor(sq[o], mk); }
    if ((tid & 63) == 0)
        #pragma unroll
        for (int o = 0; o < CO; ++o) {
            atomicAdd(&ps2[b * CO + o], sums[o]);
            atomicAdd(&pq2[b * CO + o], sq[o]);
        }
}

// ---------------------------------------------------------------- tail4: norm3 -> conv 4->1 -> logits
__global__ __launch_bounds__(256) void tail4_kernel(
    const float* __restrict__ xraw, const float* __restrict__ ps, const float* __restrict__ pq,
    const float* __restrict__ sc, const float* __restrict__ sh,
    const float* __restrict__ W4, const float* __restrict__ b4,
    float* __restrict__ out, int P)
{
    const int tid = threadIdx.x;
    const int b = blockIdx.y;
    const int p = blockIdx.x * 256 + tid;
    if (p >= P) return;
    float acc = b4[0];
    #pragma unroll
    for (int c = 0; c < 4; ++c) {
        const float S = ps[b * 4 + c], Q2 = pq[b * 4 + c];
        const float mu = S / P;
        const float var = Q2 / P - mu * mu;
        const float rs = rsqrtf(var + 1e-3f);
        const float k1 = rs * sc[c], k2 = sh[c] - mu * rs * sc[c];
        const float xn = fmaxf(xraw[((long)b * 4 + c) * P + p] * k1 + k2, 0.f);
        acc += W4[c] * xn;
    }
    out[(long)b * P + p] = acc;
}

// ================================================================ host
extern "C" void kernel_launch(void* const* d_in, const int* in_sizes, int n_in,
                              void* d_out, int out_size, void* d_ws, size_t ws_size,
                              hipStream_t stream)
{
    const float* dX   = (const float*)d_in[1];
    const float* fpX  = (const float*)d_in[2];
    const float* lgin = (const float*)d_in[3];
    const float* Wq = (const float*)d_in[4];  const float* bq = (const float*)d_in[5];
    const float* Wk = (const float*)d_in[6];  const float* bk = (const float*)d_in[7];
    const float* Wv = (const float*)d_in[8];  const float* bv = (const float*)d_in[9];
    const float* Wm = (const float*)d_in[10]; const float* bm = (const float*)d_in[11];
    const float* Wc1= (const float*)d_in[12]; const float* bc1= (const float*)d_in[13];
    const float* bns= (const float*)d_in[14]; const float* bnsh=(const float*)d_in[15];
    const float* Wc2= (const float*)d_in[16]; const float* bc2= (const float*)d_in[17];
    const float* iW1= (const float*)d_in[18]; const float* ib1= (const float*)d_in[19];
    const float* s1 = (const float*)d_in[20]; const float* h1 = (const float*)d_in[21];
    const float* iW2= (const float*)d_in[22]; const float* ib2= (const float*)d_in[23];
    const float* s2 = (const float*)d_in[24]; const float* h2 = (const float*)d_in[25];
    const float* iW3= (const float*)d_in[26]; const float* ib3= (const float*)d_in[27];
    const float* s3 = (const float*)d_in[28]; const float* h3 = (const float*)d_in[29];
    const float* iW4= (const float*)d_in[30]; const float* ib4= (const float*)d_in[31];

    float* out_d      = (float*)d_out;                 // [2,128,6000]
    float* out_logits = out_d + (long)B_ * C_ * N_;    // [2,6000]

    float* f = (float*)d_ws;
    long off = 0;
    auto alloc = [&](long n) { float* p = f + off; off += n; return p; };
    float* featA = alloc(384000);
    float* featB = alloc(384000);
    float* qb    = alloc(1536000);
    float* kb    = alloc(1536000);
    float* vb    = alloc(1536000);
    float* xb    = alloc(1536000);
    float* x1raw = alloc(768000);
    float* x2raw = alloc(192000);
    float* x3raw = alloc(48000);
    float* pmb   = alloc(100000);
    float* plb   = alloc(100000);
    float* pacc  = alloc(3200000);   // >= 8*KSmax(8)*32*Nqmax (3.07M)
    float* zst   = alloc(512);       // stats accumulators (zeroed by prep)
    float* wreg  = alloc(250000);    // 500K bf16 weights
    (void)ws_size; (void)in_sizes; (void)n_in; (void)out_size;

    float* ps1 = zst;        float* pq1 = zst + 128;
    float* ps2 = zst + 256;  float* pq2 = zst + 288;
    float* ps3 = zst + 320;  float* pq3 = zst + 328;

    u16* wq_h  = (u16*)wreg;
    u16* wk_h  = wq_h + 49152;
    u16* wv_h  = wk_h + 49152;
    u16* wm_h  = wv_h + 49152;
    u16* wc1_h = wm_h + 49152;
    u16* wc2_h = wc1_h + 196608;
    u16* w1_h  = wc2_h + 98304;

    prep_kernel<<<dim3(768), 256, 0, stream>>>(Wq, Wk, Wv, Wm, Wc1, Wc2, iW1,
                                               wq_h, wk_h, wv_h, wm_h, wc1_h, wc2_h, w1_h, zst);

    auto layer = [&](const float* x1, const float* x2, int Nq, int Nk,
                     const float* maskl, int li, int KS, int chunkLen,
                     float* outF, float* outR) {
        qkv_kernel<<<dim3((max(Nq, Nk) + 63) / 64, 6, B_), 256, 0, stream>>>(
            x1, x2, Nq, Nk,
            wq_h + (long)li * 16384, wk_h + (long)li * 16384, wv_h + (long)li * 16384,
            bq + li * 128, bk + li * 128, bv + li * 128, qb, kb, vb);
        const int qblocks = (Nq + 63) / 64;
        attn_partial<<<dim3(qblocks * KS * 8), 256, 0, stream>>>(
            qb, kb, vb, maskl, pmb, plb, pacc, Nq, Nk, KS, chunkLen);
        epi_kernel<<<dim3((Nq + 31) / 32, B_), 256, 0, stream>>>(
            pmb, plb, pacc, KS, x1,
            wm_h + (long)li * 16384, bm + li * 128,
            wc1_h + (long)li * 65536, bc1 + li * 256, bns + li * 256, bnsh + li * 256,
            wc2_h + (long)li * 32768, bc2 + li * 128,
            outF, outR, Nq);
    };

    // KS/chunk sized for >=1.5K blocks on big layers; chunk multiple of 64
    layer(fpX,   dX,    M_, N_, lgin,    0, 8, 768, featA, nullptr);   // 24*8*8  = 1536 blocks
    layer(featA, featA, M_, M_, nullptr, 1, 4, 384, featB, nullptr);   // 24*4*8  = 768
    layer(dX,    featB, N_, M_, nullptr, 2, 2, 768, out_d, xb);        // 94*2*8  = 1504

    tail1_kernel<<<dim3((N_ + 63) / 64, B_), 256, 0, stream>>>(xb, w1_h, ib1, x1raw, ps1, pq1, N_);
    tail_mid<64, 16><<<dim3((N_ + 255) / 256, B_), 256, 0, stream>>>(
        x1raw, ps1, pq1, s1, h1, iW2, ib2, ps2, pq2, x2raw, N_);
    tail_mid<16, 4><<<dim3((N_ + 255) / 256, B_), 256, 0, stream>>>(
        x2raw, ps2, pq2, s2, h2, iW3, ib3, ps3, pq3, x3raw, N_);
    tail4_kernel<<<dim3((N_ + 255) / 256, B_), 256, 0, stream>>>(
        x3raw, ps3, pq3, s3, h3, iW4, ib4, out_logits, N_);
}

// Round 7
// 397.767 us; speedup vs baseline: 2.9727x; 1.1466x over previous
//
#include <hip/hip_runtime.h>
#include <math.h>

#define B_  2
#define C_  128
#define N_  6000
#define M_  1500
#define H_  4
#define DH_ 32

typedef __attribute__((ext_vector_type(8))) short bf16x8;   // 8 bf16 = 4 VGPRs
typedef __attribute__((ext_vector_type(4))) float f32x4;
typedef unsigned short u16;

static __device__ __forceinline__ u16 f2bf(float x) {
    unsigned u = __float_as_uint(x);
    return (u16)((u + 0x7fffu + ((u >> 16) & 1u)) >> 16);   // RNE
}
#define MFMA(a,b,c) __builtin_amdgcn_mfma_f32_16x16x32_bf16((a),(b),(c),0,0,0)
// exp2-domain softmax: scores scaled by (1/sqrt(32))*log2(e)
#define INVS2 (0.17677669529663687f * 1.4426950408889634f)

// ---------------------------------------------------------------- prep: weights->bf16, zero stats
__global__ __launch_bounds__(256) void prep_kernel(
    const float* __restrict__ Wq, const float* __restrict__ Wk, const float* __restrict__ Wv,
    const float* __restrict__ Wm, const float* __restrict__ Wc1, const float* __restrict__ Wc2,
    const float* __restrict__ iW1,
    u16* __restrict__ wq, u16* __restrict__ wk, u16* __restrict__ wv, u16* __restrict__ wm,
    u16* __restrict__ wc1, u16* __restrict__ wc2, u16* __restrict__ w1,
    float* __restrict__ zstats)
{
    long i = (long)blockIdx.x * 256 + threadIdx.x;
    if (i < 512)    zstats[i] = 0.f;
    if (i < 49152)  { wq[i] = f2bf(Wq[i]); wk[i] = f2bf(Wk[i]);
                      wv[i] = f2bf(Wv[i]); wm[i] = f2bf(Wm[i]); }
    if (i < 196608) wc1[i] = f2bf(Wc1[i]);
    if (i < 98304)  wc2[i] = f2bf(Wc2[i]);
    if (i < 8192)   w1[i]  = f2bf(iW1[i]);
}

// ---------------------------------------------------------------- fused q/k/v conv (MFMA, CIN=128)
// Outputs bf16 in attention-friendly layouts:
//   Q16/K16: [bh][pos][dh]  (row = 64B)      V16: [b*128+c][key] rows padded to Ppad
__global__ __launch_bounds__(256) void qkv_kernel(
    const float* __restrict__ x1, const float* __restrict__ x2, int Pq, int Pk, int Pkpad,
    const u16* __restrict__ wq, const u16* __restrict__ wk, const u16* __restrict__ wv,
    const float* __restrict__ bq, const float* __restrict__ bk, const float* __restrict__ bv,
    u16* __restrict__ Q16, u16* __restrict__ K16, u16* __restrict__ V16)
{
    __shared__ u16 Xt[64][40];      // [pos][cin-chunk], row 80B
    const int tid = threadIdx.x;
    const int wid = tid >> 6, lane = tid & 63;
    const int l15 = lane & 15, quad = lane >> 4;
    const int job = blockIdx.y >> 1, ot = blockIdx.y & 1;
    const int b = blockIdx.z;
    const int p0 = blockIdx.x * 64;
    const float* X; const u16* W; const float* bias; u16* Y; int P;
    if (job == 0)      { X = x1; W = wq; bias = bq; Y = Q16; P = Pq; }
    else if (job == 1) { X = x2; W = wk; bias = bk; Y = K16; P = Pk; }
    else               { X = x2; W = wv; bias = bv; Y = V16; P = Pk; }
    if (p0 >= P) return;
    const long xoff = (long)b * C_ * P;
    const int sp = tid & 63, cg = tid >> 6;
    f32x4 acc[4] = {};

    for (int k0 = 0; k0 < 128; k0 += 32) {
        bf16x8 st;
        {
            const int pp = (p0 + sp < P) ? p0 + sp : P - 1;
            #pragma unroll
            for (int j = 0; j < 8; ++j)
                st[j] = (short)f2bf(X[xoff + (long)(k0 + cg * 8 + j) * P + pp]);
        }
        __syncthreads();
        *(bf16x8*)&Xt[sp][cg * 8] = st;
        __syncthreads();
        const bf16x8 af = *(const bf16x8*)(W + (long)(ot * 64 + wid * 16 + l15) * 128 + k0 + quad * 8);
        #pragma unroll
        for (int pg = 0; pg < 4; ++pg) {
            const bf16x8 bfr = *(const bf16x8*)&Xt[pg * 16 + l15][quad * 8];
            acc[pg] = MFMA(af, bfr, acc[pg]);
        }
    }
    #pragma unroll
    for (int pg = 0; pg < 4; ++pg)
        #pragma unroll
        for (int r = 0; r < 4; ++r) {
            const int o = ot * 64 + wid * 16 + quad * 4 + r;
            const int p = p0 + pg * 16 + l15;
            if (p < P) {
                const u16 v = f2bf(acc[pg][r] + bias[o]);
                if (job <= 1)   // [bh][pos][dh]
                    Y[((long)(b * 4 + (o >> 5)) * P + p) * 32 + (o & 31)] = v;
                else            // [b*128+c][key], padded rows
                    Y[(long)(b * 128 + o) * Pkpad + p] = v;
            }
        }
}

// ---------------------------------------------------------------- flash attention (MFMA, S^T, no-max exp2)
// 1D grid, id = (qblk*KS+split)*8 + bh (XCD-pins head chunks). Block = 4 independent waves,
// 32 q/wave. K/V/Q fragments loaded directly from bf16 global (L2-resident). No barriers.
__global__ __launch_bounds__(256) void attn_partial(
    const u16* __restrict__ Q16, const u16* __restrict__ K16, const u16* __restrict__ V16,
    const float* __restrict__ lgin,
    float* __restrict__ pl, float* __restrict__ pacc,
    int Nq, int Nk, int Nkpad, int KS, int chunkLen)   // chunkLen multiple of 64
{
    __shared__ u16 Ps[4][32][72];   // per-wave P round-trip, row 144B
    const int tid  = threadIdx.x;
    const int wave = tid >> 6, lane = tid & 63;
    const int l15  = lane & 15, quad = lane >> 4;
    const int bid  = blockIdx.x;
    const int bh   = bid & 7, rest = bid >> 3;
    const int split = rest % KS, qblk = rest / KS;
    const int b = bh >> 2;
    const int q0w = qblk * 128 + wave * 32;

    const u16* Qb = Q16 + (long)bh * Nq * 32;
    const u16* Kb = K16 + (long)bh * Nk * 32;
    const u16* Vb = V16 + (long)(bh * 32) * Nkpad;   // rows = dh, stride Nkpad

    // Q B-operand frags (n=q, k=dh)
    const int qq0 = min(q0w + l15, Nq - 1);
    const int qq1 = min(q0w + 16 + l15, Nq - 1);
    const bf16x8 qa0 = *(const bf16x8*)(Qb + (long)qq0 * 32 + quad * 8);
    const bf16x8 qa1 = *(const bf16x8*)(Qb + (long)qq1 * 32 + quad * 8);

    float lp0 = 0.f, lp1 = 0.f;
    f32x4 o00 = {0.f,0.f,0.f,0.f}, o01 = {0.f,0.f,0.f,0.f};   // qf0: dh 0-15, 16-31
    f32x4 o10 = {0.f,0.f,0.f,0.f}, o11 = {0.f,0.f,0.f,0.f};   // qf1

    const int kbeg = split * chunkLen;
    const int kend = min(Nk, kbeg + chunkLen);
    const f32x4 z4 = {0.f,0.f,0.f,0.f};

    for (int m0 = kbeg; m0 < kend; m0 += 64) {
        // ---- QK^T transposed: D[key][q];  A = K (m=key), B = Q (n=q)
        f32x4 sa0[4], sa1[4];
        #pragma unroll
        for (int kg = 0; kg < 4; ++kg) {
            const int krow = min(m0 + kg * 16 + l15, Nk - 1);
            const bf16x8 ka = *(const bf16x8*)(Kb + (long)krow * 32 + quad * 8);
            sa0[kg] = MFMA(ka, qa0, z4);
            sa1[kg] = MFMA(ka, qa1, z4);
        }

        const int kedge = kend - m0;     // >=64 for full tiles
        #pragma unroll
        for (int kg = 0; kg < 4; ++kg) {
            // mask per key (shared by both q-frags); keys are kg*16+quad*4+r
            float4 mv = {1.f, 1.f, 1.f, 1.f};
            if (lgin)
                mv = *(const float4*)&lgin[(long)b * Nk + min(m0 + kg * 16 + quad * 4, Nk - 4)];
            const float* mr = (const float*)&mv;
            unsigned lo0, hi0, lo1, hi1;
            float p0[4], p1[4];
            #pragma unroll
            for (int r = 0; r < 4; ++r) {
                const bool good = (kg * 16 + quad * 4 + r < kedge) && (mr[r] > 0.f);
                p0[r] = good ? exp2f(sa0[kg][r] * INVS2) : 0.f;
                p1[r] = good ? exp2f(sa1[kg][r] * INVS2) : 0.f;
            }
            lp0 += (p0[0] + p0[1]) + (p0[2] + p0[3]);
            lp1 += (p1[0] + p1[1]) + (p1[2] + p1[3]);
            lo0 = (unsigned)f2bf(p0[0]) | ((unsigned)f2bf(p0[1]) << 16);
            hi0 = (unsigned)f2bf(p0[2]) | ((unsigned)f2bf(p0[3]) << 16);
            lo1 = (unsigned)f2bf(p1[0]) | ((unsigned)f2bf(p1[1]) << 16);
            hi1 = (unsigned)f2bf(p1[2]) | ((unsigned)f2bf(p1[3]) << 16);
            *(uint2*)&Ps[wave][l15][kg * 16 + quad * 4]      = make_uint2(lo0, hi0);
            *(uint2*)&Ps[wave][16 + l15][kg * 16 + quad * 4] = make_uint2(lo1, hi1);
        }

        // ---- PV: O[q][dh];  A = P (m=q, k=key), B = V (n=dh, k=key)
        const bf16x8 pa0lo = *(const bf16x8*)&Ps[wave][l15][quad * 8];
        const bf16x8 pa0hi = *(const bf16x8*)&Ps[wave][l15][32 + quad * 8];
        const bf16x8 pa1lo = *(const bf16x8*)&Ps[wave][16 + l15][quad * 8];
        const bf16x8 pa1hi = *(const bf16x8*)&Ps[wave][16 + l15][32 + quad * 8];
        #pragma unroll
        for (int dg = 0; dg < 2; ++dg) {
            const u16* vrow = Vb + (long)(dg * 16 + l15) * Nkpad + m0;
            const bf16x8 vblo = *(const bf16x8*)(vrow + quad * 8);
            const bf16x8 vbhi = *(const bf16x8*)(vrow + 32 + quad * 8);
            if (dg == 0) {
                o00 = MFMA(pa0lo, vblo, o00); o00 = MFMA(pa0hi, vbhi, o00);
                o10 = MFMA(pa1lo, vblo, o10); o10 = MFMA(pa1hi, vbhi, o10);
            } else {
                o01 = MFMA(pa0lo, vblo, o01); o01 = MFMA(pa0hi, vbhi, o01);
                o11 = MFMA(pa1lo, vblo, o11); o11 = MFMA(pa1hi, vbhi, o11);
            }
        }
    }

    // lp: sum the 4 quad-replicas (each holds its own 16 keys)
    lp0 += __shfl_xor(lp0, 16); lp0 += __shfl_xor(lp0, 32);
    lp1 += __shfl_xor(lp1, 16); lp1 += __shfl_xor(lp1, 32);

    const long base = (long)bh * KS + split;
    if (quad == 0) {
        const int qa = q0w + l15, qbq = q0w + 16 + l15;
        if (qa  < Nq) pl[base * Nq + qa]  = lp0;
        if (qbq < Nq) pl[base * Nq + qbq] = lp1;
    }
    #pragma unroll
    for (int r = 0; r < 4; ++r) {
        const int qa = q0w + quad * 4 + r;         // qf0
        const int qbq = q0w + 16 + quad * 4 + r;   // qf1
        if (qa < Nq) {
            float* dst = &pacc[((long)base * Nq + qa) * 32];
            dst[l15] = o00[r]; dst[16 + l15] = o01[r];
        }
        if (qbq < Nq) {
            float* dst = &pacc[((long)base * Nq + qbq) * 32];
            dst[l15] = o10[r]; dst[16 + l15] = o11[r];
        }
    }
}

// ---------------------------------------------------------------- fused epilogue: combine + Wm + Wc1(BN,ReLU) + Wc2 + resid
__global__ __launch_bounds__(256) void epi_kernel(
    const float* __restrict__ pl, const float* __restrict__ pacc, int KS,
    const float* __restrict__ x1,
    const u16* __restrict__ Wm, const float* __restrict__ bm,
    const u16* __restrict__ Wc1, const float* __restrict__ bc1,
    const float* __restrict__ bns, const float* __restrict__ bnsh,
    const u16* __restrict__ Wc2, const float* __restrict__ bc2,
    float* __restrict__ outF, float* __restrict__ outR, int Nq)
{
    __shared__ u16 Xa[32][136];   // add (m-conv input), [pos][128ch]
    __shared__ u16 Xc[32][264];   // [x1 ; m], [pos][256ch]
    __shared__ u16 Xh[32][264];   // h, [pos][256ch]
    const int tid = threadIdx.x;
    const int wid = tid >> 6, lane = tid & 63;
    const int l15 = lane & 15, quad = lane >> 4;
    const int b = blockIdx.y;
    const int p0 = blockIdx.x * 32;

    // ---- phase 1: combine splits (plain sums, m==0 domain) -> Xa ; stage x1 -> Xc[:,0:128]
    {
        const int pos = tid & 31, sub = tid >> 5;
        const int pp = (p0 + pos < Nq) ? p0 + pos : Nq - 1;
        const int h = sub >> 1, d0 = (sub & 1) * 16;
        const int bh = b * 4 + h;
        float lg = 0.f, acc[16];
        #pragma unroll
        for (int i = 0; i < 16; ++i) acc[i] = 0.f;
        for (int s = 0; s < KS; ++s) {
            const long base = (long)bh * KS + s;
            lg += pl[base * Nq + pp];
            const float* src = &pacc[(base * Nq + pp) * 32 + d0];
            #pragma unroll
            for (int i = 0; i < 4; ++i) {
                const float4 v = *(const float4*)&src[i * 4];
                acc[i*4+0] += v.x; acc[i*4+1] += v.y; acc[i*4+2] += v.z; acc[i*4+3] += v.w;
            }
        }
        const float inv = 1.f / lg;
        bf16x8 v0, v1;
        #pragma unroll
        for (int i = 0; i < 8; ++i) { v0[i] = (short)f2bf(acc[i] * inv); v1[i] = (short)f2bf(acc[8 + i] * inv); }
        const int c0 = h * 32 + (sub & 1) * 16;
        *(bf16x8*)&Xa[pos][c0] = v0;
        *(bf16x8*)&Xa[pos][c0 + 8] = v1;
        bf16x8 y0, y1;
        #pragma unroll
        for (int j = 0; j < 8; ++j) {
            y0[j] = (short)f2bf(x1[((long)b * 128 + sub * 16 + j) * Nq + pp]);
            y1[j] = (short)f2bf(x1[((long)b * 128 + sub * 16 + 8 + j) * Nq + pp]);
        }
        *(bf16x8*)&Xc[pos][sub * 16] = y0;
        *(bf16x8*)&Xc[pos][sub * 16 + 8] = y1;
    }
    __syncthreads();

    // ---- phase 2: m = Wm*add + bm -> Xc[:,128:256]
    {
        f32x4 am[2][2] = {};
        for (int k0 = 0; k0 < 128; k0 += 32) {
            #pragma unroll
            for (int og = 0; og < 2; ++og) {
                const bf16x8 af = *(const bf16x8*)(Wm + (long)(wid * 32 + og * 16 + l15) * 128 + k0 + quad * 8);
                #pragma unroll
                for (int pg = 0; pg < 2; ++pg) {
                    const bf16x8 bfr = *(const bf16x8*)&Xa[pg * 16 + l15][k0 + quad * 8];
                    am[og][pg] = MFMA(af, bfr, am[og][pg]);
                }
            }
        }
        #pragma unroll
        for (int og = 0; og < 2; ++og)
            #pragma unroll
            for (int pg = 0; pg < 2; ++pg)
                #pragma unroll
                for (int r = 0; r < 4; ++r) {
                    const int o = wid * 32 + og * 16 + quad * 4 + r;
                    Xc[pg * 16 + l15][128 + o] = f2bf(am[og][pg][r] + bm[o]);
                }
    }
    __syncthreads();

    // ---- phase 3: h = relu(bns*(Wc1*[x1;m]+bc1)+bnsh) -> Xh
    {
        f32x4 a1[4][2] = {};
        for (int k0 = 0; k0 < 256; k0 += 32) {
            #pragma unroll
            for (int og = 0; og < 4; ++og) {
                const bf16x8 af = *(const bf16x8*)(Wc1 + (long)(wid * 64 + og * 16 + l15) * 256 + k0 + quad * 8);
                #pragma unroll
                for (int pg = 0; pg < 2; ++pg) {
                    const bf16x8 bfr = *(const bf16x8*)&Xc[pg * 16 + l15][k0 + quad * 8];
                    a1[og][pg] = MFMA(af, bfr, a1[og][pg]);
                }
            }
        }
        #pragma unroll
        for (int og = 0; og < 4; ++og)
            #pragma unroll
            for (int pg = 0; pg < 2; ++pg)
                #pragma unroll
                for (int r = 0; r < 4; ++r) {
                    const int o = wid * 64 + og * 16 + quad * 4 + r;
                    const float hv = fmaxf((a1[og][pg][r] + bc1[o]) * bns[o] + bnsh[o], 0.f);
                    Xh[pg * 16 + l15][o] = f2bf(hv);
                }
    }
    __syncthreads();

    // ---- phase 4: y = Wc2*h + bc2 (+x1 resid) -> outF (+outR raw)
    {
        f32x4 a2[2][2] = {};
        for (int k0 = 0; k0 < 256; k0 += 32) {
            #pragma unroll
            for (int og = 0; og < 2; ++og) {
                const bf16x8 af = *(const bf16x8*)(Wc2 + (long)(wid * 32 + og * 16 + l15) * 256 + k0 + quad * 8);
                #pragma unroll
                for (int pg = 0; pg < 2; ++pg) {
                    const bf16x8 bfr = *(const bf16x8*)&Xh[pg * 16 + l15][k0 + quad * 8];
                    a2[og][pg] = MFMA(af, bfr, a2[og][pg]);
                }
            }
        }
        #pragma unroll
        for (int og = 0; og < 2; ++og)
            #pragma unroll
            for (int pg = 0; pg < 2; ++pg)
                #pragma unroll
                for (int r = 0; r < 4; ++r) {
                    const int o = wid * 32 + og * 16 + quad * 4 + r;
                    const int p = p0 + pg * 16 + l15;
                    if (p < Nq) {
                        const long idx = ((long)b * 128 + o) * Nq + p;
                        const float v = a2[og][pg][r] + bc2[o];
                        outF[idx] = v + x1[idx];
                        if (outR) outR[idx] = v;
                    }
                }
    }
}

// ---------------------------------------------------------------- tail1: conv 128->64 (MFMA) + atomic stats
__global__ __launch_bounds__(256) void tail1_kernel(
    const float* __restrict__ X, const u16* __restrict__ W, const float* __restrict__ bias,
    float* __restrict__ Y, float* __restrict__ ps, float* __restrict__ pq, int P)
{
    __shared__ u16 Xt[64][40];
    const int tid = threadIdx.x;
    const int wid = tid >> 6, lane = tid & 63;
    const int l15 = lane & 15, quad = lane >> 4;
    const int b = blockIdx.y;
    const int p0 = blockIdx.x * 64;
    const int sp = tid & 63, cg = tid >> 6;
    f32x4 acc[4] = {};
    for (int k0 = 0; k0 < 128; k0 += 32) {
        bf16x8 st;
        {
            const int pp = (p0 + sp < P) ? p0 + sp : P - 1;
            #pragma unroll
            for (int j = 0; j < 8; ++j)
                st[j] = (short)f2bf(X[((long)b * 128 + k0 + cg * 8 + j) * P + pp]);
        }
        __syncthreads();
        *(bf16x8*)&Xt[sp][cg * 8] = st;
        __syncthreads();
        const bf16x8 af = *(const bf16x8*)(W + (long)(wid * 16 + l15) * 128 + k0 + quad * 8);
        #pragma unroll
        for (int pg = 0; pg < 4; ++pg) {
            const bf16x8 bfr = *(const bf16x8*)&Xt[pg * 16 + l15][quad * 8];
            acc[pg] = MFMA(af, bfr, acc[pg]);
        }
    }
    float sums[4] = {}, sq[4] = {};
    #pragma unroll
    for (int pg = 0; pg < 4; ++pg)
        #pragma unroll
        for (int r = 0; r < 4; ++r) {
            const int o = wid * 16 + quad * 4 + r;
            const int p = p0 + pg * 16 + l15;
            if (p < P) {
                const float v = acc[pg][r] + bias[o];
                Y[((long)b * 64 + o) * P + p] = v;
                sums[r] += v; sq[r] += v * v;
            }
        }
    #pragma unroll
    for (int mk = 1; mk < 16; mk <<= 1)
        #pragma unroll
        for (int r = 0; r < 4; ++r) { sums[r] += __shfl_xor(sums[r], mk); sq[r] += __shfl_xor(sq[r], mk); }
    if (l15 == 0)
        #pragma unroll
        for (int r = 0; r < 4; ++r) {
            const int o = wid * 16 + quad * 4 + r;
            atomicAdd(&ps[b * 64 + o], sums[r]);
            atomicAdd(&pq[b * 64 + o], sq[r]);
        }
}

// ---------------------------------------------------------------- tail mid: norm(prev) -> conv -> stats
template<int CI, int CO>
__global__ __launch_bounds__(256) void tail_mid(
    const float* __restrict__ xraw, const float* __restrict__ ps, const float* __restrict__ pq,
    const float* __restrict__ sc, const float* __restrict__ sh,
    const float* __restrict__ W, const float* __restrict__ bias,
    float* __restrict__ ps2, float* __restrict__ pq2, float* __restrict__ yraw, int P)
{
    __shared__ float k1s[CI], k2s[CI], Wl[CO * CI];
    const int tid = threadIdx.x;
    const int b = blockIdx.y;
    for (int i = tid; i < CO * CI; i += 256) Wl[i] = W[i];
    if (tid < CI) {
        const float S = ps[b * CI + tid], Q2 = pq[b * CI + tid];
        const float mu = S / P;
        const float var = Q2 / P - mu * mu;
        const float rs = rsqrtf(var + 1e-3f);
        k1s[tid] = rs * sc[tid];
        k2s[tid] = sh[tid] - mu * rs * sc[tid];
    }
    __syncthreads();
    const int p = blockIdx.x * 256 + tid;
    const bool valid = p < P;
    const int pp = valid ? p : P - 1;
    float acc[CO];
    #pragma unroll
    for (int o = 0; o < CO; ++o) acc[o] = bias[o];
    for (int c = 0; c < CI; ++c) {
        const float xn = fmaxf(xraw[((long)b * CI + c) * P + pp] * k1s[c] + k2s[c], 0.f);
        #pragma unroll
        for (int o = 0; o < CO; ++o) acc[o] += Wl[o * CI + c] * xn;
    }
    float sums[CO], sq[CO];
    #pragma unroll
    for (int o = 0; o < CO; ++o) {
        const float v = acc[o];
        if (valid) yraw[((long)b * CO + o) * P + p] = v;
        sums[o] = valid ? v : 0.f;
        sq[o] = valid ? v * v : 0.f;
    }
    #pragma unroll
    for (int mk = 1; mk < 64; mk <<= 1)
        #pragma unroll
        for (int o = 0; o < CO; ++o) { sums[o] += __shfl_xor(sums[o], mk); sq[o] += __shfl_xor(sq[o], mk); }
    if ((tid & 63) == 0)
        #pragma unroll
        for (int o = 0; o < CO; ++o) {
            atomicAdd(&ps2[b * CO + o], sums[o]);
            atomicAdd(&pq2[b * CO + o], sq[o]);
        }
}

// ---------------------------------------------------------------- tail4: norm3 -> conv 4->1 -> logits
__global__ __launch_bounds__(256) void tail4_kernel(
    const float* __restrict__ xraw, const float* __restrict__ ps, const float* __restrict__ pq,
    const float* __restrict__ sc, const float* __restrict__ sh,
    const float* __restrict__ W4, const float* __restrict__ b4,
    float* __restrict__ out, int P)
{
    const int tid = threadIdx.x;
    const int b = blockIdx.y;
    const int p = blockIdx.x * 256 + tid;
    if (p >= P) return;
    float acc = b4[0];
    #pragma unroll
    for (int c = 0; c < 4; ++c) {
        const float S = ps[b * 4 + c], Q2 = pq[b * 4 + c];
        const float mu = S / P;
        const float var = Q2 / P - mu * mu;
        const float rs = rsqrtf(var + 1e-3f);
        const float k1 = rs * sc[c], k2 = sh[c] - mu * rs * sc[c];
        const float xn = fmaxf(xraw[((long)b * 4 + c) * P + p] * k1 + k2, 0.f);
        acc += W4[c] * xn;
    }
    out[(long)b * P + p] = acc;
}

// ================================================================ host
extern "C" void kernel_launch(void* const* d_in, const int* in_sizes, int n_in,
                              void* d_out, int out_size, void* d_ws, size_t ws_size,
                              hipStream_t stream)
{
    const float* dX   = (const float*)d_in[1];
    const float* fpX  = (const float*)d_in[2];
    const float* lgin = (const float*)d_in[3];
    const float* Wq = (const float*)d_in[4];  const float* bq = (const float*)d_in[5];
    const float* Wk = (const float*)d_in[6];  const float* bk = (const float*)d_in[7];
    const float* Wv = (const float*)d_in[8];  const float* bv = (const float*)d_in[9];
    const float* Wm = (const float*)d_in[10]; const float* bm = (const float*)d_in[11];
    const float* Wc1= (const float*)d_in[12]; const float* bc1= (const float*)d_in[13];
    const float* bns= (const float*)d_in[14]; const float* bnsh=(const float*)d_in[15];
    const float* Wc2= (const float*)d_in[16]; const float* bc2= (const float*)d_in[17];
    const float* iW1= (const float*)d_in[18]; const float* ib1= (const float*)d_in[19];
    const float* s1 = (const float*)d_in[20]; const float* h1 = (const float*)d_in[21];
    const float* iW2= (const float*)d_in[22]; const float* ib2= (const float*)d_in[23];
    const float* s2 = (const float*)d_in[24]; const float* h2 = (const float*)d_in[25];
    const float* iW3= (const float*)d_in[26]; const float* ib3= (const float*)d_in[27];
    const float* s3 = (const float*)d_in[28]; const float* h3 = (const float*)d_in[29];
    const float* iW4= (const float*)d_in[30]; const float* ib4= (const float*)d_in[31];

    float* out_d      = (float*)d_out;                 // [2,128,6000]
    float* out_logits = out_d + (long)B_ * C_ * N_;    // [2,6000]

    float* f = (float*)d_ws;
    long off = 0;
    auto alloc = [&](long n) { float* p = f + off; off += n; return p; };
    float* featA = alloc(384000);
    float* featB = alloc(384000);
    float* q16f  = alloc(800000);    // 1.6M u16: Q16 [8][Nq][32]
    float* k16f  = alloc(800000);    // K16 [8][Nk][32]
    float* v16f  = alloc(800000);    // V16 [256][Nkpad]
    float* xb    = alloc(1536000);
    float* x1raw = alloc(768000);
    float* x2raw = alloc(192000);
    float* x3raw = alloc(48000);
    float* plb   = alloc(100000);
    float* pacc  = alloc(3200000);   // >= 8*KS*Nq*32 (3.07M max)
    float* zst   = alloc(512);       // stats accumulators (zeroed by prep)
    float* wreg  = alloc(250000);    // 500K bf16 weights
    (void)ws_size; (void)in_sizes; (void)n_in; (void)out_size;

    float* ps1 = zst;        float* pq1 = zst + 128;
    float* ps2 = zst + 256;  float* pq2 = zst + 288;
    float* ps3 = zst + 320;  float* pq3 = zst + 328;

    u16* wq_h  = (u16*)wreg;
    u16* wk_h  = wq_h + 49152;
    u16* wv_h  = wk_h + 49152;
    u16* wm_h  = wv_h + 49152;
    u16* wc1_h = wm_h + 49152;
    u16* wc2_h = wc1_h + 196608;
    u16* w1_h  = wc2_h + 98304;

    u16* Q16 = (u16*)q16f;
    u16* K16 = (u16*)k16f;
    u16* V16 = (u16*)v16f;

    prep_kernel<<<dim3(768), 256, 0, stream>>>(Wq, Wk, Wv, Wm, Wc1, Wc2, iW1,
                                               wq_h, wk_h, wv_h, wm_h, wc1_h, wc2_h, w1_h, zst);

    auto layer = [&](const float* x1, const float* x2, int Nq, int Nk,
                     const float* maskl, int li, int KS, int chunkLen,
                     float* outF, float* outR) {
        const int Nkpad = ((Nk + 63) & ~63) + 64;   // V rows padded; loads may run past Nk
        qkv_kernel<<<dim3((max(Nq, Nk) + 63) / 64, 6, B_), 256, 0, stream>>>(
            x1, x2, Nq, Nk, Nkpad,
            wq_h + (long)li * 16384, wk_h + (long)li * 16384, wv_h + (long)li * 16384,
            bq + li * 128, bk + li * 128, bv + li * 128, Q16, K16, V16);
        const int qblocks = (Nq + 127) / 128;
        attn_partial<<<dim3(qblocks * KS * 8), 256, 0, stream>>>(
            Q16, K16, V16, maskl, plb, pacc, Nq, Nk, Nkpad, KS, chunkLen);
        epi_kernel<<<dim3((Nq + 31) / 32, B_), 256, 0, stream>>>(
            plb, pacc, KS, x1,
            wm_h + (long)li * 16384, bm + li * 128,
            wc1_h + (long)li * 65536, bc1 + li * 256, bns + li * 256, bnsh + li * 256,
            wc2_h + (long)li * 32768, bc2 + li * 128,
            outF, outR, Nq);
    };

    // blocks: L0 12*8*8=768, L1 12*8*8=768, L2 47*2*8=752; chunk multiple of 64
    layer(fpX,   dX,    M_, N_, lgin,    0, 8, 768, featA, nullptr);
    layer(featA, featA, M_, M_, nullptr, 1, 8, 192, featB, nullptr);
    layer(dX,    featB, N_, M_, nullptr, 2, 2, 768, out_d, xb);

    tail1_kernel<<<dim3((N_ + 63) / 64, B_), 256, 0, stream>>>(xb, w1_h, ib1, x1raw, ps1, pq1, N_);
    tail_mid<64, 16><<<dim3((N_ + 255) / 256, B_), 256, 0, stream>>>(
        x1raw, ps1, pq1, s1, h1, iW2, ib2, ps2, pq2, x2raw, N_);
    tail_mid<16, 4><<<dim3((N_ + 255) / 256, B_), 256, 0, stream>>>(
        x2raw, ps2, pq2, s2, h2, iW3, ib3, ps3, pq3, x3raw, N_);
    tail4_kernel<<<dim3((N_ + 255) / 256, B_), 256, 0, stream>>>(
        x3raw, ps3, pq3, s3, h3, iW4, ib4, out_logits, N_);
}